// Round 1
// baseline (669.974 us; speedup 1.0000x reference)
//
#include <hip/hip_runtime.h>
#include <math.h>

#define NN 50000
#define EE 800000
#define DIN 300
#define DH 128
#define NG 128

__device__ __forceinline__ float gelu_exact(float x) {
  return 0.5f * x * (1.0f + erff(x * 0.7071067811865476f));
}

// ---------------- CSR build ----------------

__global__ __launch_bounds__(256) void count_deg_kernel(const int* __restrict__ ei,
                                                        int* __restrict__ deg) {
  int e = blockIdx.x * 256 + threadIdx.x;
  if (e >= EE + NN) return;
  int d = (e < EE) ? ei[EE + e] : (e - EE);  // dst; self-loops appended
  atomicAdd(&deg[d], 1);
}

__global__ __launch_bounds__(1024) void scan_kernel(const int* __restrict__ deg,
                                                    int* __restrict__ rowptr) {
  __shared__ int wsum[16];
  __shared__ int carry_s;
  const int tid = threadIdx.x;
  const int lane = tid & 63;
  const int wid = tid >> 6;
  if (tid == 0) carry_s = 0;
  __syncthreads();
  for (int base = 0; base < NN; base += 1024) {
    int idx = base + tid;
    int v = (idx < NN) ? deg[idx] : 0;
    int x = v;
#pragma unroll
    for (int d = 1; d < 64; d <<= 1) {
      int y = __shfl_up(x, d, 64);
      if (lane >= d) x += y;
    }
    if (lane == 63) wsum[wid] = x;
    __syncthreads();
    if (wid == 0) {
      int s = (lane < 16) ? wsum[lane] : 0;
#pragma unroll
      for (int d = 1; d < 16; d <<= 1) {
        int y = __shfl_up(s, d, 64);
        if (lane >= d) s += y;
      }
      if (lane < 16) wsum[lane] = s;
    }
    __syncthreads();
    int waveoff = (wid > 0) ? wsum[wid - 1] : 0;
    int incl = x + waveoff + carry_s;
    if (idx < NN) rowptr[idx] = incl - v;  // exclusive
    __syncthreads();
    if (tid == 1023) carry_s = incl;
    __syncthreads();
  }
  if (tid == 0) rowptr[NN] = carry_s;
}

__global__ __launch_bounds__(256) void scatter_kernel(const int* __restrict__ ei,
                                                      int* __restrict__ cursor,
                                                      int* __restrict__ colA) {
  int e = blockIdx.x * 256 + threadIdx.x;
  if (e >= EE + NN) return;
  int s, d;
  if (e < EE) { s = ei[e]; d = ei[EE + e]; }
  else        { s = e - EE; d = e - EE; }
  int p = atomicAdd(&cursor[d], 1);
  colA[p] = s;
}

// ---------------- fp32 GEMM: C[M,128] = A[M,K] @ B[K,128] ----------------
// Block: 256 threads, tile 64 rows x 128 cols, K chunks of 16.

__global__ __launch_bounds__(256) void gemm_kernel(const float* __restrict__ A,
                                                   const float* __restrict__ B,
                                                   float* __restrict__ C,
                                                   int M, int K) {
  __shared__ float As[64][17];   // +1 pad: conflict-free reads
  __shared__ float Bs[16][128];
  const int tid = threadIdx.x;
  const int tx = tid & 15;       // col group: cols tx*8 .. tx*8+7
  const int ty = tid >> 4;       // row group: rows ty*4 .. ty*4+3
  const int row0 = blockIdx.x * 64;

  float acc[4][8];
#pragma unroll
  for (int i = 0; i < 4; i++)
#pragma unroll
    for (int j = 0; j < 8; j++) acc[i][j] = 0.f;

  for (int k0 = 0; k0 < K; k0 += 16) {
    // stage A: 64x16
#pragma unroll
    for (int p = 0; p < 4; p++) {
      int r = (tid >> 4) + p * 16;
      int k = tid & 15;
      int gr = row0 + r, gk = k0 + k;
      As[r][k] = (gr < M && gk < K) ? A[(long)gr * K + gk] : 0.f;
    }
    // stage B: 16x128
#pragma unroll
    for (int p = 0; p < 8; p++) {
      int idx = tid + p * 256;
      int k = idx >> 7, n = idx & 127;
      int gk = k0 + k;
      Bs[k][n] = (gk < K) ? B[(long)gk * 128 + n] : 0.f;
    }
    __syncthreads();
#pragma unroll
    for (int kk = 0; kk < 16; kk++) {
      float a0 = As[ty * 4 + 0][kk];
      float a1 = As[ty * 4 + 1][kk];
      float a2 = As[ty * 4 + 2][kk];
      float a3 = As[ty * 4 + 3][kk];
      float b[8];
#pragma unroll
      for (int j = 0; j < 8; j++) b[j] = Bs[kk][tx * 8 + j];
#pragma unroll
      for (int j = 0; j < 8; j++) {
        acc[0][j] = fmaf(a0, b[j], acc[0][j]);
        acc[1][j] = fmaf(a1, b[j], acc[1][j]);
        acc[2][j] = fmaf(a2, b[j], acc[2][j]);
        acc[3][j] = fmaf(a3, b[j], acc[3][j]);
      }
    }
    __syncthreads();
  }
#pragma unroll
  for (int i = 0; i < 4; i++) {
    int gr = row0 + ty * 4 + i;
    if (gr < M) {
      float4* p = (float4*)&C[(long)gr * 128 + tx * 8];
      p[0] = make_float4(acc[i][0], acc[i][1], acc[i][2], acc[i][3]);
      p[1] = make_float4(acc[i][4], acc[i][5], acc[i][6], acc[i][7]);
    }
  }
}

// ---------------- per-node attention coefficients: aS = h@att_src, aD = h@att_dst ----------------

__global__ __launch_bounds__(256) void rowdot_kernel(const float* __restrict__ H,
                                                     const float* __restrict__ avs,
                                                     const float* __restrict__ avd,
                                                     float* __restrict__ aS,
                                                     float* __restrict__ aD) {
  int lane = threadIdx.x & 63;
  int w = threadIdx.x >> 6;
  int n = blockIdx.x * 4 + w;
  if (n >= NN) return;
  float h0 = H[(long)n * DH + lane];
  float h1 = H[(long)n * DH + 64 + lane];
  float ds = h0 * avs[lane] + h1 * avs[64 + lane];
  float dd = h0 * avd[lane] + h1 * avd[64 + lane];
#pragma unroll
  for (int d = 1; d < 64; d <<= 1) {
    ds += __shfl_xor(ds, d, 64);
    dd += __shfl_xor(dd, d, 64);
  }
  if (lane == 0) { aS[n] = ds; aD[n] = dd; }
}

// ---------------- softmax attention + aggregation, one block (128 thr) per dst ----------------

__global__ __launch_bounds__(128) void aggregate_kernel(const int* __restrict__ rowptr,
                                                        const int* __restrict__ colA,
                                                        const float* __restrict__ aS,
                                                        const float* __restrict__ aD,
                                                        const float* __restrict__ H,
                                                        const float* __restrict__ bias,
                                                        float* __restrict__ out,
                                                        int apply_gelu) {
  const int dst = blockIdx.x;
  const int tid = threadIdx.x;
  const int lane = tid & 63;
  const int w = tid >> 6;
  const int start = rowptr[dst];
  const int end = rowptr[dst + 1];
  const int deg = end - start;

  __shared__ int s_src[128];
  __shared__ float s_e[128];
  __shared__ float s_redA[2];
  __shared__ float s_redB[2];

  const float ad = aD[dst];
  float m = -__builtin_inff();
  float ssum = 0.f;

  // online-softmax stats over chunks of 128 edges
  for (int c0 = start; c0 < end; c0 += 128) {
    int i = c0 + tid;
    float e = -__builtin_inff();
    if (i < end) {
      int s = colA[i];
      float v = aS[s] + ad;
      e = (v > 0.f) ? v : 0.2f * v;  // leaky_relu 0.2
      s_src[tid] = s;
      s_e[tid] = e;
    }
    float cm = e;
#pragma unroll
    for (int d = 1; d < 64; d <<= 1) cm = fmaxf(cm, __shfl_xor(cm, d, 64));
    if (lane == 0) s_redA[w] = cm;
    __syncthreads();
    cm = fmaxf(s_redA[0], s_redA[1]);
    float ce = (i < end) ? expf(e - cm) : 0.f;
    float cs = ce;
#pragma unroll
    for (int d = 1; d < 64; d <<= 1) cs += __shfl_xor(cs, d, 64);
    if (lane == 0) s_redB[w] = cs;
    __syncthreads();
    cs = s_redB[0] + s_redB[1];
    // combine chunk (cm, cs) into running (m, ssum)
    float nm = fmaxf(m, cm);
    ssum = ssum * expf(m - nm) + cs * expf(cm - nm);
    m = nm;
  }

  const float inv = 1.f / ssum;
  float accv = 0.f;

  if (deg <= 128) {
    // s_src / s_e still hold the single chunk
    if (tid < deg) s_e[tid] = expf(s_e[tid] - m) * inv;  // weight
    __syncthreads();
#pragma unroll 4
    for (int i = 0; i < deg; i++) {
      accv = fmaf(s_e[i], H[(long)s_src[i] * DH + tid], accv);
    }
  } else {
    // general path (practically never taken; max degree ~45)
    for (int c0 = start; c0 < end; c0 += 128) {
      __syncthreads();
      int i = c0 + tid;
      if (i < end) {
        int s = colA[i];
        float v = aS[s] + ad;
        float e = (v > 0.f) ? v : 0.2f * v;
        s_src[tid] = s;
        s_e[tid] = expf(e - m) * inv;
      }
      __syncthreads();
      int lim = min(128, end - c0);
      for (int j = 0; j < lim; j++) {
        accv = fmaf(s_e[j], H[(long)s_src[j] * DH + tid], accv);
      }
    }
  }

  float r = accv + bias[tid];
  if (apply_gelu) r = gelu_exact(r);
  out[(long)dst * DH + tid] = r;
}

// ---------------- masked per-graph mean pooling (batch is sorted) ----------------

__global__ __launch_bounds__(128) void pool_kernel(const float* __restrict__ H,
                                                   const int* __restrict__ batch,
                                                   const int* __restrict__ pos,
                                                   float* __restrict__ sums,
                                                   float* __restrict__ cnt) {
  const int CH = 64;
  int n0 = blockIdx.x * CH;
  int n1 = min(n0 + CH, NN);
  int f = threadIdx.x;
  float acc = 0.f, c = 0.f;
  int g = batch[n0];
  for (int n = n0; n < n1; n++) {
    int gn = batch[n];
    if (gn != g) {
      atomicAdd(&sums[g * DH + f], acc);
      if (f == 0) atomicAdd(&cnt[g], c);
      acc = 0.f; c = 0.f; g = gn;
    }
    if (pos[n]) {
      acc += H[(long)n * DH + f];
      c += 1.f;
    }
  }
  atomicAdd(&sums[g * DH + f], acc);
  if (f == 0) atomicAdd(&cnt[g], c);
}

// ---------------- head: logits + gelu + fc ----------------

__global__ __launch_bounds__(128) void head_kernel(const float* __restrict__ sums,
                                                   const float* __restrict__ cnt,
                                                   const float* __restrict__ Wfc,
                                                   const float* __restrict__ bfc,
                                                   float* __restrict__ out) {
  int g = blockIdx.x;
  int f = threadIdx.x;
  float c = fmaxf(cnt[g], 1.f);
  float logit = sums[g * DH + f] / c;
  out[NG + g * DH + f] = logit;  // logits output (after 128 scores)
  float gl = gelu_exact(logit) * Wfc[f];
  __shared__ float red[2];
#pragma unroll
  for (int d = 1; d < 64; d <<= 1) gl += __shfl_xor(gl, d, 64);
  int lane = f & 63, w = f >> 6;
  if (lane == 0) red[w] = gl;
  __syncthreads();
  if (f == 0) out[g] = red[0] + red[1] + bfc[0];
}

// ---------------- launch ----------------

extern "C" void kernel_launch(void* const* d_in, const int* in_sizes, int n_in,
                              void* d_out, int out_size, void* d_ws, size_t ws_size,
                              hipStream_t stream) {
  const float* x   = (const float*)d_in[0];
  const int* ei    = (const int*)d_in[1];
  const int* batch = (const int*)d_in[2];
  const int* pos   = (const int*)d_in[3];
  // d_in[4] = num_graphs (scalar) — compile-time constant NG
  const float* W1  = (const float*)d_in[5];
  const float* as1 = (const float*)d_in[6];
  const float* ad1 = (const float*)d_in[7];
  const float* b1  = (const float*)d_in[8];
  const float* W2  = (const float*)d_in[9];
  const float* as2 = (const float*)d_in[10];
  const float* ad2 = (const float*)d_in[11];
  const float* b2  = (const float*)d_in[12];
  const float* Wfc = (const float*)d_in[13];
  const float* bfc = (const float*)d_in[14];
  float* out = (float*)d_out;

  char* ws = (char*)d_ws;
  size_t off = 0;
  auto nxt = [&](size_t b) -> void* {
    size_t p = off;
    off += (b + 255) & ~(size_t)255;
    return (void*)(ws + p);
  };
  int* rowptr = (int*)nxt((NN + 1) * sizeof(int));
  int* cursor = (int*)nxt(NN * sizeof(int));
  int* colA   = (int*)nxt((size_t)(EE + NN) * sizeof(int));
  float* aS   = (float*)nxt(NN * sizeof(float));
  float* aD   = (float*)nxt(NN * sizeof(float));
  float* bufA = (float*)nxt((size_t)NN * DH * sizeof(float));
  float* bufB = (float*)nxt((size_t)NN * DH * sizeof(float));
  float* sums = (float*)nxt((size_t)(NG * DH + NG) * sizeof(float));
  float* cnt  = sums + NG * DH;

  hipMemsetAsync(cursor, 0, NN * sizeof(int), stream);
  hipMemsetAsync(sums, 0, (NG * DH + NG) * sizeof(float), stream);

  const int eb = (EE + NN + 255) / 256;
  count_deg_kernel<<<eb, 256, 0, stream>>>(ei, cursor);
  scan_kernel<<<1, 1024, 0, stream>>>(cursor, rowptr);
  hipMemcpyAsync(cursor, rowptr, NN * sizeof(int), hipMemcpyDeviceToDevice, stream);
  scatter_kernel<<<eb, 256, 0, stream>>>(ei, cursor, colA);

  const int gb = (NN + 63) / 64;
  // layer 1
  gemm_kernel<<<gb, 256, 0, stream>>>(x, W1, bufA, NN, DIN);
  rowdot_kernel<<<NN / 4, 256, 0, stream>>>(bufA, as1, ad1, aS, aD);
  aggregate_kernel<<<NN, 128, 0, stream>>>(rowptr, colA, aS, aD, bufA, b1, bufB, 1);
  // layer 2
  gemm_kernel<<<gb, 256, 0, stream>>>(bufB, W2, bufA, NN, DH);
  rowdot_kernel<<<NN / 4, 256, 0, stream>>>(bufA, as2, ad2, aS, aD);
  aggregate_kernel<<<NN, 128, 0, stream>>>(rowptr, colA, aS, aD, bufA, b2, bufB, 0);
  // pooling + head
  pool_kernel<<<gb, 128, 0, stream>>>(bufB, batch, pos, sums, cnt);
  head_kernel<<<NG, 128, 0, stream>>>(sums, cnt, Wfc, bfc, out);
}

// Round 2
// 557.977 us; speedup vs baseline: 1.2007x; 1.2007x over previous
//
#include <hip/hip_runtime.h>
#include <math.h>

#define NN 50000
#define EE 800000
#define DIN 300
#define DH 128
#define NG 128

__device__ __forceinline__ float gelu_exact(float x) {
  return 0.5f * x * (1.0f + erff(x * 0.7071067811865476f));
}

// ---------------- CSR build ----------------

__global__ __launch_bounds__(256) void count_deg_kernel(const int* __restrict__ ei,
                                                        int* __restrict__ deg) {
  int e = blockIdx.x * 256 + threadIdx.x;
  if (e >= EE + NN) return;
  int d = (e < EE) ? ei[EE + e] : (e - EE);  // dst; self-loops appended
  atomicAdd(&deg[d], 1);
}

__global__ __launch_bounds__(1024) void scan_kernel(const int* __restrict__ deg,
                                                    int* __restrict__ rowptr) {
  __shared__ int wsum[16];
  __shared__ int carry_s;
  const int tid = threadIdx.x;
  const int lane = tid & 63;
  const int wid = tid >> 6;
  if (tid == 0) carry_s = 0;
  __syncthreads();
  for (int base = 0; base < NN; base += 1024) {
    int idx = base + tid;
    int v = (idx < NN) ? deg[idx] : 0;
    int x = v;
#pragma unroll
    for (int d = 1; d < 64; d <<= 1) {
      int y = __shfl_up(x, d, 64);
      if (lane >= d) x += y;
    }
    if (lane == 63) wsum[wid] = x;
    __syncthreads();
    if (wid == 0) {
      int s = (lane < 16) ? wsum[lane] : 0;
#pragma unroll
      for (int d = 1; d < 16; d <<= 1) {
        int y = __shfl_up(s, d, 64);
        if (lane >= d) s += y;
      }
      if (lane < 16) wsum[lane] = s;
    }
    __syncthreads();
    int waveoff = (wid > 0) ? wsum[wid - 1] : 0;
    int incl = x + waveoff + carry_s;
    if (idx < NN) rowptr[idx] = incl - v;  // exclusive
    __syncthreads();
    if (tid == 1023) carry_s = incl;
    __syncthreads();
  }
  if (tid == 0) rowptr[NN] = carry_s;
}

__global__ __launch_bounds__(256) void scatter_kernel(const int* __restrict__ ei,
                                                      int* __restrict__ cursor,
                                                      int* __restrict__ colA) {
  int e = blockIdx.x * 256 + threadIdx.x;
  if (e >= EE + NN) return;
  int s, d;
  if (e < EE) { s = ei[e]; d = ei[EE + e]; }
  else        { s = e - EE; d = e - EE; }
  int p = atomicAdd(&cursor[d], 1);
  colA[p] = s;
}

// ---------------- fp32 GEMM + fused attention row-dots ----------------
// C[M,128] = A[M,K] @ B[K,128]; also aS[r] += C_row . avs, aD[r] += C_row . avd
// Grid: (ceil(M/64), 2). Block 256 = 16(tx) x 16(ty); thread tile 4 rows x 4 cols.
// BK=32. A staged K-major (As[k][row]) so compute reads are ds_read_b128.

__global__ __launch_bounds__(256) void gemm_att_kernel(
    const float* __restrict__ A, const float* __restrict__ B,
    float* __restrict__ C, int M, int K,
    const float* __restrict__ avs, const float* __restrict__ avd,
    float* __restrict__ aS, float* __restrict__ aD) {
  __shared__ __align__(16) float As[32][68];  // [k][row], pad 68: aligned b128, low conflict
  __shared__ __align__(16) float Bs[32][68];  // [k][col]
  const int tid = threadIdx.x;
  const int tx = tid & 15;   // col group: c0 + tx*4 .. +3
  const int ty = tid >> 4;   // row group: row0 + ty*4 .. +3
  const int row0 = blockIdx.x * 64;
  const int c0 = blockIdx.y * 64;

  float acc[4][4];
#pragma unroll
  for (int i = 0; i < 4; i++)
#pragma unroll
    for (int j = 0; j < 4; j++) acc[i][j] = 0.f;

  for (int k0 = 0; k0 < K; k0 += 32) {
    // stage A: 64 rows x 32 k, transposed into As[k][row]
#pragma unroll
    for (int p = 0; p < 8; p++) {
      int e = p * 256 + tid;
      int r = e >> 5, k = e & 31;
      int gr = row0 + r, gk = k0 + k;
      As[k][r] = (gr < M && gk < K) ? A[(long)gr * K + gk] : 0.f;
    }
    // stage B: 32 k x 64 cols (vectorized, B rows are 512B-aligned)
#pragma unroll
    for (int p = 0; p < 2; p++) {
      int f = p * 256 + tid;
      int k = f >> 4, nq = f & 15;
      int gk = k0 + k;
      float4 v = make_float4(0.f, 0.f, 0.f, 0.f);
      if (gk < K) v = *(const float4*)&B[(long)gk * 128 + c0 + nq * 4];
      *(float4*)&Bs[k][nq * 4] = v;
    }
    __syncthreads();
#pragma unroll
    for (int kk = 0; kk < 32; kk++) {
      float4 a = *(const float4*)&As[kk][ty * 4];
      float4 b = *(const float4*)&Bs[kk][tx * 4];
      acc[0][0] = fmaf(a.x, b.x, acc[0][0]);
      acc[0][1] = fmaf(a.x, b.y, acc[0][1]);
      acc[0][2] = fmaf(a.x, b.z, acc[0][2]);
      acc[0][3] = fmaf(a.x, b.w, acc[0][3]);
      acc[1][0] = fmaf(a.y, b.x, acc[1][0]);
      acc[1][1] = fmaf(a.y, b.y, acc[1][1]);
      acc[1][2] = fmaf(a.y, b.z, acc[1][2]);
      acc[1][3] = fmaf(a.y, b.w, acc[1][3]);
      acc[2][0] = fmaf(a.z, b.x, acc[2][0]);
      acc[2][1] = fmaf(a.z, b.y, acc[2][1]);
      acc[2][2] = fmaf(a.z, b.z, acc[2][2]);
      acc[2][3] = fmaf(a.z, b.w, acc[2][3]);
      acc[3][0] = fmaf(a.w, b.x, acc[3][0]);
      acc[3][1] = fmaf(a.w, b.y, acc[3][1]);
      acc[3][2] = fmaf(a.w, b.z, acc[3][2]);
      acc[3][3] = fmaf(a.w, b.w, acc[3][3]);
    }
    __syncthreads();
  }

  // epilogue: store C, fused row-dots with att vectors (16-lane reduce + atomic)
  float4 vs4 = *(const float4*)&avs[c0 + tx * 4];
  float4 vd4 = *(const float4*)&avd[c0 + tx * 4];
#pragma unroll
  for (int i = 0; i < 4; i++) {
    int gr = row0 + ty * 4 + i;
    if (gr < M) {
      *(float4*)&C[(long)gr * 128 + c0 + tx * 4] =
          make_float4(acc[i][0], acc[i][1], acc[i][2], acc[i][3]);
      float ps = acc[i][0] * vs4.x + acc[i][1] * vs4.y + acc[i][2] * vs4.z + acc[i][3] * vs4.w;
      float pd = acc[i][0] * vd4.x + acc[i][1] * vd4.y + acc[i][2] * vd4.z + acc[i][3] * vd4.w;
#pragma unroll
      for (int d = 1; d < 16; d <<= 1) {
        ps += __shfl_xor(ps, d, 16);
        pd += __shfl_xor(pd, d, 16);
      }
      if (tx == 0) {
        atomicAdd(&aS[gr], ps);
        atomicAdd(&aD[gr], pd);
      }
    }
  }
}

// ---------------- softmax attention + aggregation, one block (128 thr) per dst ----------------

__global__ __launch_bounds__(128) void aggregate_kernel(const int* __restrict__ rowptr,
                                                        const int* __restrict__ colA,
                                                        const float* __restrict__ aS,
                                                        const float* __restrict__ aD,
                                                        const float* __restrict__ H,
                                                        const float* __restrict__ bias,
                                                        float* __restrict__ out,
                                                        int apply_gelu) {
  const int dst = blockIdx.x;
  const int tid = threadIdx.x;
  const int lane = tid & 63;
  const int w = tid >> 6;
  const int start = rowptr[dst];
  const int end = rowptr[dst + 1];
  const int deg = end - start;

  __shared__ int s_src[128];
  __shared__ float s_e[128];
  __shared__ float s_redA[2];
  __shared__ float s_redB[2];

  const float ad = aD[dst];
  float m = -__builtin_inff();
  float ssum = 0.f;

  // online-softmax stats over chunks of 128 edges
  for (int c0 = start; c0 < end; c0 += 128) {
    int i = c0 + tid;
    float e = -__builtin_inff();
    if (i < end) {
      int s = colA[i];
      float v = aS[s] + ad;
      e = (v > 0.f) ? v : 0.2f * v;  // leaky_relu 0.2
      s_src[tid] = s;
      s_e[tid] = e;
    }
    float cm = e;
#pragma unroll
    for (int d = 1; d < 64; d <<= 1) cm = fmaxf(cm, __shfl_xor(cm, d, 64));
    if (lane == 0) s_redA[w] = cm;
    __syncthreads();
    cm = fmaxf(s_redA[0], s_redA[1]);
    float ce = (i < end) ? expf(e - cm) : 0.f;
    float cs = ce;
#pragma unroll
    for (int d = 1; d < 64; d <<= 1) cs += __shfl_xor(cs, d, 64);
    if (lane == 0) s_redB[w] = cs;
    __syncthreads();
    cs = s_redB[0] + s_redB[1];
    float nm = fmaxf(m, cm);
    ssum = ssum * expf(m - nm) + cs * expf(cm - nm);
    m = nm;
  }

  const float inv = 1.f / ssum;
  float accv = 0.f;

  if (deg <= 128) {
    if (tid < deg) s_e[tid] = expf(s_e[tid] - m) * inv;  // weight
    __syncthreads();
#pragma unroll 4
    for (int i = 0; i < deg; i++) {
      accv = fmaf(s_e[i], H[(long)s_src[i] * DH + tid], accv);
    }
  } else {
    for (int c0 = start; c0 < end; c0 += 128) {
      __syncthreads();
      int i = c0 + tid;
      if (i < end) {
        int s = colA[i];
        float v = aS[s] + ad;
        float e = (v > 0.f) ? v : 0.2f * v;
        s_src[tid] = s;
        s_e[tid] = expf(e - m) * inv;
      }
      __syncthreads();
      int lim = min(128, end - c0);
      for (int j = 0; j < lim; j++) {
        accv = fmaf(s_e[j], H[(long)s_src[j] * DH + tid], accv);
      }
    }
  }

  float r = accv + bias[tid];
  if (apply_gelu) r = gelu_exact(r);
  out[(long)dst * DH + tid] = r;
}

// ---------------- masked per-graph mean pooling (batch is sorted) ----------------

__global__ __launch_bounds__(128) void pool_kernel(const float* __restrict__ H,
                                                   const int* __restrict__ batch,
                                                   const int* __restrict__ pos,
                                                   float* __restrict__ sums,
                                                   float* __restrict__ cnt) {
  const int CH = 64;
  int n0 = blockIdx.x * CH;
  int n1 = min(n0 + CH, NN);
  int f = threadIdx.x;
  float acc = 0.f, c = 0.f;
  int g = batch[n0];
  for (int n = n0; n < n1; n++) {
    int gn = batch[n];
    if (gn != g) {
      atomicAdd(&sums[g * DH + f], acc);
      if (f == 0) atomicAdd(&cnt[g], c);
      acc = 0.f; c = 0.f; g = gn;
    }
    if (pos[n]) {
      acc += H[(long)n * DH + f];
      c += 1.f;
    }
  }
  atomicAdd(&sums[g * DH + f], acc);
  if (f == 0) atomicAdd(&cnt[g], c);
}

// ---------------- head: logits + gelu + fc ----------------

__global__ __launch_bounds__(128) void head_kernel(const float* __restrict__ sums,
                                                   const float* __restrict__ cnt,
                                                   const float* __restrict__ Wfc,
                                                   const float* __restrict__ bfc,
                                                   float* __restrict__ out) {
  int g = blockIdx.x;
  int f = threadIdx.x;
  float c = fmaxf(cnt[g], 1.f);
  float logit = sums[g * DH + f] / c;
  out[NG + g * DH + f] = logit;  // logits output (after 128 scores)
  float gl = gelu_exact(logit) * Wfc[f];
  __shared__ float red[2];
#pragma unroll
  for (int d = 1; d < 64; d <<= 1) gl += __shfl_xor(gl, d, 64);
  int lane = f & 63, w = f >> 6;
  if (lane == 0) red[w] = gl;
  __syncthreads();
  if (f == 0) out[g] = red[0] + red[1] + bfc[0];
}

// ---------------- launch ----------------

extern "C" void kernel_launch(void* const* d_in, const int* in_sizes, int n_in,
                              void* d_out, int out_size, void* d_ws, size_t ws_size,
                              hipStream_t stream) {
  const float* x   = (const float*)d_in[0];
  const int* ei    = (const int*)d_in[1];
  const int* batch = (const int*)d_in[2];
  const int* pos   = (const int*)d_in[3];
  const float* W1  = (const float*)d_in[5];
  const float* as1 = (const float*)d_in[6];
  const float* ad1 = (const float*)d_in[7];
  const float* b1  = (const float*)d_in[8];
  const float* W2  = (const float*)d_in[9];
  const float* as2 = (const float*)d_in[10];
  const float* ad2 = (const float*)d_in[11];
  const float* b2  = (const float*)d_in[12];
  const float* Wfc = (const float*)d_in[13];
  const float* bfc = (const float*)d_in[14];
  float* out = (float*)d_out;

  char* ws = (char*)d_ws;
  size_t off = 0;
  auto nxt = [&](size_t b) -> void* {
    size_t p = off;
    off += (b + 255) & ~(size_t)255;
    return (void*)(ws + p);
  };
  int* rowptr = (int*)nxt((NN + 1) * sizeof(int));
  int* cursor = (int*)nxt(NN * sizeof(int));
  int* colA   = (int*)nxt((size_t)(EE + NN) * sizeof(int));
  float* aS   = (float*)nxt((size_t)2 * NN * sizeof(float));
  float* aD   = aS + NN;
  float* bufA = (float*)nxt((size_t)NN * DH * sizeof(float));
  float* bufB = (float*)nxt((size_t)NN * DH * sizeof(float));
  float* sums = (float*)nxt((size_t)(NG * DH + NG) * sizeof(float));
  float* cnt  = sums + NG * DH;

  hipMemsetAsync(cursor, 0, NN * sizeof(int), stream);
  hipMemsetAsync(sums, 0, (NG * DH + NG) * sizeof(float), stream);
  hipMemsetAsync(aS, 0, (size_t)2 * NN * sizeof(float), stream);

  const int eb = (EE + NN + 255) / 256;
  count_deg_kernel<<<eb, 256, 0, stream>>>(ei, cursor);
  scan_kernel<<<1, 1024, 0, stream>>>(cursor, rowptr);
  hipMemcpyAsync(cursor, rowptr, NN * sizeof(int), hipMemcpyDeviceToDevice, stream);
  scatter_kernel<<<eb, 256, 0, stream>>>(ei, cursor, colA);

  const dim3 ggrid((NN + 63) / 64, 2);
  // layer 1 (GEMM fuses the att_src/att_dst row-dots)
  gemm_att_kernel<<<ggrid, 256, 0, stream>>>(x, W1, bufA, NN, DIN, as1, ad1, aS, aD);
  aggregate_kernel<<<NN, 128, 0, stream>>>(rowptr, colA, aS, aD, bufA, b1, bufB, 1);
  // layer 2
  hipMemsetAsync(aS, 0, (size_t)2 * NN * sizeof(float), stream);
  gemm_att_kernel<<<ggrid, 256, 0, stream>>>(bufB, W2, bufA, NN, DH, as2, ad2, aS, aD);
  aggregate_kernel<<<NN, 128, 0, stream>>>(rowptr, colA, aS, aD, bufA, b2, bufB, 0);
  // pooling + head
  pool_kernel<<<(NN + 63) / 64, 128, 0, stream>>>(bufB, batch, pos, sums, cnt);
  head_kernel<<<NG, 128, 0, stream>>>(sums, cnt, Wfc, bfc, out);
}

// Round 3
// 488.917 us; speedup vs baseline: 1.3703x; 1.1413x over previous
//
#include <hip/hip_runtime.h>
#include <math.h>

#define NN 50000
#define EE 800000
#define DIN 300
#define DH 128
#define NG 128
#define LDA 40  // LDS row stride in bf16 units (pad 32 -> 40: conflict-free b128)

typedef __attribute__((ext_vector_type(8))) short short8;
typedef __attribute__((ext_vector_type(4))) float floatx4;

__device__ __forceinline__ float gelu_exact(float x) {
  return 0.5f * x * (1.0f + erff(x * 0.7071067811865476f));
}

__device__ __forceinline__ void split_bf16(float v, unsigned short& hi, unsigned short& lo) {
  unsigned int u = __float_as_uint(v);
  hi = (unsigned short)(u >> 16);
  float fh = __uint_as_float((unsigned int)hi << 16);
  lo = (unsigned short)(__float_as_uint(v - fh) >> 16);
}

// ---------------- CSR build ----------------

__global__ __launch_bounds__(256) void count_deg_kernel(const int* __restrict__ ei,
                                                        int* __restrict__ deg) {
  int e = blockIdx.x * 256 + threadIdx.x;
  if (e >= EE + NN) return;
  int d = (e < EE) ? ei[EE + e] : (e - EE);
  atomicAdd(&deg[d], 1);
}

__global__ __launch_bounds__(1024) void scan_kernel(const int* __restrict__ deg,
                                                    int* __restrict__ rowptr) {
  __shared__ int wsum[16];
  __shared__ int carry_s;
  const int tid = threadIdx.x;
  const int lane = tid & 63;
  const int wid = tid >> 6;
  if (tid == 0) carry_s = 0;
  __syncthreads();
  for (int base = 0; base < NN; base += 1024) {
    int idx = base + tid;
    int v = (idx < NN) ? deg[idx] : 0;
    int x = v;
#pragma unroll
    for (int d = 1; d < 64; d <<= 1) {
      int y = __shfl_up(x, d, 64);
      if (lane >= d) x += y;
    }
    if (lane == 63) wsum[wid] = x;
    __syncthreads();
    if (wid == 0) {
      int s = (lane < 16) ? wsum[lane] : 0;
#pragma unroll
      for (int d = 1; d < 16; d <<= 1) {
        int y = __shfl_up(s, d, 64);
        if (lane >= d) s += y;
      }
      if (lane < 16) wsum[lane] = s;
    }
    __syncthreads();
    int waveoff = (wid > 0) ? wsum[wid - 1] : 0;
    int incl = x + waveoff + carry_s;
    if (idx < NN) rowptr[idx] = incl - v;
    __syncthreads();
    if (tid == 1023) carry_s = incl;
    __syncthreads();
  }
  if (tid == 0) rowptr[NN] = carry_s;
}

__global__ __launch_bounds__(256) void scatter_kernel(const int* __restrict__ ei,
                                                      int* __restrict__ cursor,
                                                      int* __restrict__ colA) {
  int e = blockIdx.x * 256 + threadIdx.x;
  if (e >= EE + NN) return;
  int s, d;
  if (e < EE) { s = ei[e]; d = ei[EE + e]; }
  else        { s = e - EE; d = e - EE; }
  int p = atomicAdd(&cursor[d], 1);
  colA[p] = s;
}

// ---------------- B pre-transpose + split to bf16 hi/lo ----------------
// B[K][128] fp32 row-major  ->  Bt_h/Bt_l [128][Kpad] bf16, zero-padded.

__global__ __launch_bounds__(256) void convert_bt_kernel(const float* __restrict__ B,
                                                         unsigned short* __restrict__ Bth,
                                                         unsigned short* __restrict__ Btl,
                                                         int K, int Kpad) {
  int i = blockIdx.x * 256 + threadIdx.x;
  int n = i / Kpad, k = i % Kpad;
  if (n >= 128) return;
  float v = (k < K) ? B[(long)k * 128 + n] : 0.f;
  unsigned short h, l;
  split_bf16(v, h, l);
  Bth[(long)n * Kpad + k] = h;
  Btl[(long)n * Kpad + k] = l;
}

// ---------------- MFMA split-bf16 GEMM + fused attention row-dots ----------------
// C[M,128] = A[M,K] @ B[K,128]  (A fp32, B pre-split bf16 transposed)
// Block 256 thr = 4 waves in 2x2 grid; BM=128, BN=128, BK=32.
// Each wave: 4x4 tiles of 16x16 via v_mfma_f32_16x16x32_bf16, 3 MFMAs per tile (hh, hl, lh).

__global__ __launch_bounds__(256) void gemm_mfma_kernel(
    const float* __restrict__ A,
    const unsigned short* __restrict__ Bth, const unsigned short* __restrict__ Btl,
    float* __restrict__ C, int M, int K, int Kpad,
    const float* __restrict__ avs, const float* __restrict__ avd,
    float* __restrict__ aS, float* __restrict__ aD) {
  __shared__ unsigned short Ah[128 * LDA];
  __shared__ unsigned short Al[128 * LDA];
  __shared__ unsigned short Bh[128 * LDA];
  __shared__ unsigned short Bl[128 * LDA];

  const int tid = threadIdx.x;
  const int lane = tid & 63;
  const int w = tid >> 6;
  const int wr = w >> 1, wc = w & 1;
  const int q = lane >> 4;     // quad 0..3
  const int m16 = lane & 15;
  const int row0 = blockIdx.x * 128;

  floatx4 acc[4][4];
#pragma unroll
  for (int i = 0; i < 4; i++)
#pragma unroll
    for (int j = 0; j < 4; j++) acc[i][j] = (floatx4)(0.f);

  const int nsteps = Kpad / 32;
  for (int s = 0; s < nsteps; s++) {
    const int k0 = s * 32;
    // ---- stage A: 128 rows x 32 k, fp32 -> hi/lo bf16 (K % 4 == 0 for our shapes)
#pragma unroll
    for (int p = 0; p < 4; p++) {
      int e = p * 256 + tid;   // 0..1023
      int r = e >> 3;          // 0..127
      int q4 = e & 7;          // float4 index within the 32-k chunk
      int gr = row0 + r, gk = k0 + q4 * 4;
      float4 v = make_float4(0.f, 0.f, 0.f, 0.f);
      if (gr < M && gk < K) v = *(const float4*)&A[(long)gr * K + gk];
      unsigned short h0, h1, h2, h3, l0, l1, l2, l3;
      split_bf16(v.x, h0, l0);
      split_bf16(v.y, h1, l1);
      split_bf16(v.z, h2, l2);
      split_bf16(v.w, h3, l3);
      uint2 hh, ll;
      hh.x = (unsigned)h0 | ((unsigned)h1 << 16);
      hh.y = (unsigned)h2 | ((unsigned)h3 << 16);
      ll.x = (unsigned)l0 | ((unsigned)l1 << 16);
      ll.y = (unsigned)l2 | ((unsigned)l3 << 16);
      *(uint2*)&Ah[r * LDA + q4 * 4] = hh;
      *(uint2*)&Al[r * LDA + q4 * 4] = ll;
    }
    // ---- stage B: [n][k] bf16 planes, straight copies from pre-split Bt
#pragma unroll
    for (int p = 0; p < 2; p++) {
      int e = p * 256 + tid;   // 0..511
      int n = e & 127;
      int sel = e >> 7;        // 0: Bh lo-half, 1: Bh hi-half, 2: Bl lo-half, 3: Bl hi-half
      const unsigned short* src = (sel & 2) ? Btl : Bth;
      unsigned short* dst = (sel & 2) ? Bl : Bh;
      int kk = (sel & 1) * 16;
      uint4 v0 = *(const uint4*)&src[(long)n * Kpad + k0 + kk];
      uint4 v1 = *(const uint4*)&src[(long)n * Kpad + k0 + kk + 8];
      *(uint4*)&dst[n * LDA + kk] = v0;
      *(uint4*)&dst[n * LDA + kk + 8] = v1;
    }
    __syncthreads();
    // ---- compute
    short8 afh[4], afl[4];
#pragma unroll
    for (int rt = 0; rt < 4; rt++) {
      int r = wr * 64 + rt * 16 + m16;
      afh[rt] = *(const short8*)&Ah[r * LDA + q * 8];
      afl[rt] = *(const short8*)&Al[r * LDA + q * 8];
    }
#pragma unroll
    for (int ct = 0; ct < 4; ct++) {
      int n = wc * 64 + ct * 16 + m16;
      short8 bfh = *(const short8*)&Bh[n * LDA + q * 8];
      short8 bfl = *(const short8*)&Bl[n * LDA + q * 8];
#pragma unroll
      for (int rt = 0; rt < 4; rt++) {
        acc[rt][ct] = __builtin_amdgcn_mfma_f32_16x16x32_bf16(afh[rt], bfh, acc[rt][ct], 0, 0, 0);
        acc[rt][ct] = __builtin_amdgcn_mfma_f32_16x16x32_bf16(afh[rt], bfl, acc[rt][ct], 0, 0, 0);
        acc[rt][ct] = __builtin_amdgcn_mfma_f32_16x16x32_bf16(afl[rt], bfh, acc[rt][ct], 0, 0, 0);
      }
    }
    __syncthreads();
  }

  // ---- epilogue: store C (layout col=lane&15, row=quad*4+reg) + fused row-dots
  float avs_r[4], avd_r[4];
#pragma unroll
  for (int ct = 0; ct < 4; ct++) {
    int n = wc * 64 + ct * 16 + m16;
    avs_r[ct] = avs[n];
    avd_r[ct] = avd[n];
  }
#pragma unroll
  for (int rt = 0; rt < 4; rt++) {
    int rbase = row0 + wr * 64 + rt * 16 + q * 4;
#pragma unroll
    for (int reg = 0; reg < 4; reg++) {
      int grow = rbase + reg;
      bool ok = grow < M;
      float ps = 0.f, pd = 0.f;
#pragma unroll
      for (int ct = 0; ct < 4; ct++) {
        float c = acc[rt][ct][reg];
        if (ok) C[(long)grow * 128 + wc * 64 + ct * 16 + m16] = c;
        ps = fmaf(c, avs_r[ct], ps);
        pd = fmaf(c, avd_r[ct], pd);
      }
#pragma unroll
      for (int d = 1; d < 16; d <<= 1) {
        ps += __shfl_xor(ps, d, 64);
        pd += __shfl_xor(pd, d, 64);
      }
      if (m16 == 0 && ok) {
        atomicAdd(&aS[grow], ps);
        atomicAdd(&aD[grow], pd);
      }
    }
  }
}

// ---------------- softmax attention + aggregation, one block (128 thr) per dst ----------------

__global__ __launch_bounds__(128) void aggregate_kernel(const int* __restrict__ rowptr,
                                                        const int* __restrict__ colA,
                                                        const float* __restrict__ aS,
                                                        const float* __restrict__ aD,
                                                        const float* __restrict__ H,
                                                        const float* __restrict__ bias,
                                                        float* __restrict__ out,
                                                        int apply_gelu) {
  const int dst = blockIdx.x;
  const int tid = threadIdx.x;
  const int lane = tid & 63;
  const int w = tid >> 6;
  const int start = rowptr[dst];
  const int end = rowptr[dst + 1];
  const int deg = end - start;

  __shared__ int s_src[128];
  __shared__ float s_e[128];
  __shared__ float s_redA[2];
  __shared__ float s_redB[2];

  const float ad = aD[dst];
  float m = -__builtin_inff();
  float ssum = 0.f;

  for (int c0 = start; c0 < end; c0 += 128) {
    int i = c0 + tid;
    float e = -__builtin_inff();
    if (i < end) {
      int s = colA[i];
      float v = aS[s] + ad;
      e = (v > 0.f) ? v : 0.2f * v;
      s_src[tid] = s;
      s_e[tid] = e;
    }
    float cm = e;
#pragma unroll
    for (int d = 1; d < 64; d <<= 1) cm = fmaxf(cm, __shfl_xor(cm, d, 64));
    if (lane == 0) s_redA[w] = cm;
    __syncthreads();
    cm = fmaxf(s_redA[0], s_redA[1]);
    float ce = (i < end) ? expf(e - cm) : 0.f;
    float cs = ce;
#pragma unroll
    for (int d = 1; d < 64; d <<= 1) cs += __shfl_xor(cs, d, 64);
    if (lane == 0) s_redB[w] = cs;
    __syncthreads();
    cs = s_redB[0] + s_redB[1];
    float nm = fmaxf(m, cm);
    ssum = ssum * expf(m - nm) + cs * expf(cm - nm);
    m = nm;
  }

  const float inv = 1.f / ssum;
  float accv = 0.f;

  if (deg <= 128) {
    if (tid < deg) s_e[tid] = expf(s_e[tid] - m) * inv;
    __syncthreads();
#pragma unroll 4
    for (int i = 0; i < deg; i++) {
      accv = fmaf(s_e[i], H[(long)s_src[i] * DH + tid], accv);
    }
  } else {
    for (int c0 = start; c0 < end; c0 += 128) {
      __syncthreads();
      int i = c0 + tid;
      if (i < end) {
        int s = colA[i];
        float v = aS[s] + ad;
        float e = (v > 0.f) ? v : 0.2f * v;
        s_src[tid] = s;
        s_e[tid] = expf(e - m) * inv;
      }
      __syncthreads();
      int lim = min(128, end - c0);
      for (int j = 0; j < lim; j++) {
        accv = fmaf(s_e[j], H[(long)s_src[j] * DH + tid], accv);
      }
    }
  }

  float r = accv + bias[tid];
  if (apply_gelu) r = gelu_exact(r);
  out[(long)dst * DH + tid] = r;
}

// ---------------- masked per-graph mean pooling (batch is sorted) ----------------

__global__ __launch_bounds__(128) void pool_kernel(const float* __restrict__ H,
                                                   const int* __restrict__ batch,
                                                   const int* __restrict__ pos,
                                                   float* __restrict__ sums,
                                                   float* __restrict__ cnt) {
  const int CH = 64;
  int n0 = blockIdx.x * CH;
  int n1 = min(n0 + CH, NN);
  int f = threadIdx.x;
  float acc = 0.f, c = 0.f;
  int g = batch[n0];
  for (int n = n0; n < n1; n++) {
    int gn = batch[n];
    if (gn != g) {
      atomicAdd(&sums[g * DH + f], acc);
      if (f == 0) atomicAdd(&cnt[g], c);
      acc = 0.f; c = 0.f; g = gn;
    }
    if (pos[n]) {
      acc += H[(long)n * DH + f];
      c += 1.f;
    }
  }
  atomicAdd(&sums[g * DH + f], acc);
  if (f == 0) atomicAdd(&cnt[g], c);
}

// ---------------- head: logits + gelu + fc ----------------

__global__ __launch_bounds__(128) void head_kernel(const float* __restrict__ sums,
                                                   const float* __restrict__ cnt,
                                                   const float* __restrict__ Wfc,
                                                   const float* __restrict__ bfc,
                                                   float* __restrict__ out) {
  int g = blockIdx.x;
  int f = threadIdx.x;
  float c = fmaxf(cnt[g], 1.f);
  float logit = sums[g * DH + f] / c;
  out[NG + g * DH + f] = logit;
  float gl = gelu_exact(logit) * Wfc[f];
  __shared__ float red[2];
#pragma unroll
  for (int d = 1; d < 64; d <<= 1) gl += __shfl_xor(gl, d, 64);
  int lane = f & 63, w = f >> 6;
  if (lane == 0) red[w] = gl;
  __syncthreads();
  if (f == 0) out[g] = red[0] + red[1] + bfc[0];
}

// ---------------- launch ----------------

extern "C" void kernel_launch(void* const* d_in, const int* in_sizes, int n_in,
                              void* d_out, int out_size, void* d_ws, size_t ws_size,
                              hipStream_t stream) {
  const float* x   = (const float*)d_in[0];
  const int* ei    = (const int*)d_in[1];
  const int* batch = (const int*)d_in[2];
  const int* pos   = (const int*)d_in[3];
  const float* W1  = (const float*)d_in[5];
  const float* as1 = (const float*)d_in[6];
  const float* ad1 = (const float*)d_in[7];
  const float* b1  = (const float*)d_in[8];
  const float* W2  = (const float*)d_in[9];
  const float* as2 = (const float*)d_in[10];
  const float* ad2 = (const float*)d_in[11];
  const float* b2  = (const float*)d_in[12];
  const float* Wfc = (const float*)d_in[13];
  const float* bfc = (const float*)d_in[14];
  float* out = (float*)d_out;

  const int KP1 = 320;  // 300 padded to 32
  const int KP2 = 128;

  char* ws = (char*)d_ws;
  size_t off = 0;
  auto nxt = [&](size_t b) -> void* {
    size_t p = off;
    off += (b + 255) & ~(size_t)255;
    return (void*)(ws + p);
  };
  int* rowptr = (int*)nxt((NN + 1) * sizeof(int));
  int* cursor = (int*)nxt(NN * sizeof(int));
  int* colA   = (int*)nxt((size_t)(EE + NN) * sizeof(int));
  float* aS   = (float*)nxt((size_t)2 * NN * sizeof(float));
  float* aD   = aS + NN;
  float* bufA = (float*)nxt((size_t)NN * DH * sizeof(float));
  float* bufB = (float*)nxt((size_t)NN * DH * sizeof(float));
  float* sums = (float*)nxt((size_t)(NG * DH + NG) * sizeof(float));
  float* cnt  = sums + NG * DH;
  unsigned short* Bt1h = (unsigned short*)nxt((size_t)128 * KP1 * sizeof(short));
  unsigned short* Bt1l = (unsigned short*)nxt((size_t)128 * KP1 * sizeof(short));
  unsigned short* Bt2h = (unsigned short*)nxt((size_t)128 * KP2 * sizeof(short));
  unsigned short* Bt2l = (unsigned short*)nxt((size_t)128 * KP2 * sizeof(short));

  hipMemsetAsync(cursor, 0, NN * sizeof(int), stream);
  hipMemsetAsync(sums, 0, (NG * DH + NG) * sizeof(float), stream);
  hipMemsetAsync(aS, 0, (size_t)2 * NN * sizeof(float), stream);

  // weight conversions (tiny)
  convert_bt_kernel<<<(128 * KP1 + 255) / 256, 256, 0, stream>>>(W1, Bt1h, Bt1l, DIN, KP1);
  convert_bt_kernel<<<(128 * KP2 + 255) / 256, 256, 0, stream>>>(W2, Bt2h, Bt2l, DH, KP2);

  const int eb = (EE + NN + 255) / 256;
  count_deg_kernel<<<eb, 256, 0, stream>>>(ei, cursor);
  scan_kernel<<<1, 1024, 0, stream>>>(cursor, rowptr);
  hipMemcpyAsync(cursor, rowptr, NN * sizeof(int), hipMemcpyDeviceToDevice, stream);
  scatter_kernel<<<eb, 256, 0, stream>>>(ei, cursor, colA);

  const int gblocks = (NN + 127) / 128;
  // layer 1
  gemm_mfma_kernel<<<gblocks, 256, 0, stream>>>(x, Bt1h, Bt1l, bufA, NN, DIN, KP1,
                                                as1, ad1, aS, aD);
  aggregate_kernel<<<NN, 128, 0, stream>>>(rowptr, colA, aS, aD, bufA, b1, bufB, 1);
  // layer 2
  hipMemsetAsync(aS, 0, (size_t)2 * NN * sizeof(float), stream);
  gemm_mfma_kernel<<<gblocks, 256, 0, stream>>>(bufB, Bt2h, Bt2l, bufA, NN, DH, KP2,
                                                as2, ad2, aS, aD);
  aggregate_kernel<<<NN, 128, 0, stream>>>(rowptr, colA, aS, aD, bufA, b2, bufB, 0);
  // pooling + head
  pool_kernel<<<(NN + 63) / 64, 128, 0, stream>>>(bufB, batch, pos, sums, cnt);
  head_kernel<<<NG, 128, 0, stream>>>(sums, cnt, Wfc, bfc, out);
}

// Round 4
// 471.941 us; speedup vs baseline: 1.4196x; 1.0360x over previous
//
#include <hip/hip_runtime.h>
#include <math.h>

#define NN 50000
#define EE 800000
#define DIN 300
#define DH 128
#define NG 128
#define LDA 40  // LDS row stride in bf16 units (pad 32 -> 40: conflict-free b128)

typedef __attribute__((ext_vector_type(8))) short short8;
typedef __attribute__((ext_vector_type(4))) float floatx4;

__device__ __forceinline__ float gelu_exact(float x) {
  return 0.5f * x * (1.0f + erff(x * 0.7071067811865476f));
}

__device__ __forceinline__ void split_bf16(float v, unsigned short& hi, unsigned short& lo) {
  unsigned int u = __float_as_uint(v);
  hi = (unsigned short)(u >> 16);
  float fh = __uint_as_float((unsigned int)hi << 16);
  lo = (unsigned short)(__float_as_uint(v - fh) >> 16);
}

__device__ __forceinline__ unsigned short f2bf_rne(float x) {
  unsigned int u = __float_as_uint(x);
  unsigned int r = (u + 0x7FFFu + ((u >> 16) & 1u)) >> 16;
  return (unsigned short)r;
}

// ---------------- CSR build ----------------

__global__ __launch_bounds__(256) void count_deg_kernel(const int* __restrict__ ei,
                                                        int* __restrict__ deg) {
  int e = blockIdx.x * 256 + threadIdx.x;
  if (e >= EE + NN) return;
  int d = (e < EE) ? ei[EE + e] : (e - EE);
  atomicAdd(&deg[d], 1);
}

__global__ __launch_bounds__(1024) void scan_kernel(const int* __restrict__ deg,
                                                    int* __restrict__ rowptr) {
  __shared__ int wsum[16];
  __shared__ int carry_s;
  const int tid = threadIdx.x;
  const int lane = tid & 63;
  const int wid = tid >> 6;
  if (tid == 0) carry_s = 0;
  __syncthreads();
  for (int base = 0; base < NN; base += 1024) {
    int idx = base + tid;
    int v = (idx < NN) ? deg[idx] : 0;
    int x = v;
#pragma unroll
    for (int d = 1; d < 64; d <<= 1) {
      int y = __shfl_up(x, d, 64);
      if (lane >= d) x += y;
    }
    if (lane == 63) wsum[wid] = x;
    __syncthreads();
    if (wid == 0) {
      int s = (lane < 16) ? wsum[lane] : 0;
#pragma unroll
      for (int d = 1; d < 16; d <<= 1) {
        int y = __shfl_up(s, d, 64);
        if (lane >= d) s += y;
      }
      if (lane < 16) wsum[lane] = s;
    }
    __syncthreads();
    int waveoff = (wid > 0) ? wsum[wid - 1] : 0;
    int incl = x + waveoff + carry_s;
    if (idx < NN) rowptr[idx] = incl - v;
    __syncthreads();
    if (tid == 1023) carry_s = incl;
    __syncthreads();
  }
  if (tid == 0) rowptr[NN] = carry_s;
}

__global__ __launch_bounds__(256) void scatter_kernel(const int* __restrict__ ei,
                                                      int* __restrict__ cursor,
                                                      int* __restrict__ colA) {
  int e = blockIdx.x * 256 + threadIdx.x;
  if (e >= EE + NN) return;
  int s, d;
  if (e < EE) { s = ei[e]; d = ei[EE + e]; }
  else        { s = e - EE; d = e - EE; }
  int p = atomicAdd(&cursor[d], 1);
  colA[p] = s;
}

// ---------------- B pre-transpose + split to bf16 hi/lo ----------------

__global__ __launch_bounds__(256) void convert_bt_kernel(const float* __restrict__ B,
                                                         unsigned short* __restrict__ Bth,
                                                         unsigned short* __restrict__ Btl,
                                                         int K, int Kpad) {
  int i = blockIdx.x * 256 + threadIdx.x;
  int n = i / Kpad, k = i % Kpad;
  if (n >= 128) return;
  float v = (k < K) ? B[(long)k * 128 + n] : 0.f;
  unsigned short h, l;
  split_bf16(v, h, l);
  Bth[(long)n * Kpad + k] = h;
  Btl[(long)n * Kpad + k] = l;
}

// ---------------- MFMA split-bf16 GEMM + fused attention row-dots ----------------
// C (bf16) [M,128] = A[M,K] @ B[K,128]; aS/aD from fp32 accumulators.

__global__ __launch_bounds__(256) void gemm_mfma_kernel(
    const float* __restrict__ A,
    const unsigned short* __restrict__ Bth, const unsigned short* __restrict__ Btl,
    unsigned short* __restrict__ C, int M, int K, int Kpad,
    const float* __restrict__ avs, const float* __restrict__ avd,
    float* __restrict__ aS, float* __restrict__ aD) {
  __shared__ unsigned short Ah[128 * LDA];
  __shared__ unsigned short Al[128 * LDA];
  __shared__ unsigned short Bh[128 * LDA];
  __shared__ unsigned short Bl[128 * LDA];

  const int tid = threadIdx.x;
  const int lane = tid & 63;
  const int w = tid >> 6;
  const int wr = w >> 1, wc = w & 1;
  const int q = lane >> 4;
  const int m16 = lane & 15;
  const int row0 = blockIdx.x * 128;

  floatx4 acc[4][4];
#pragma unroll
  for (int i = 0; i < 4; i++)
#pragma unroll
    for (int j = 0; j < 4; j++) acc[i][j] = (floatx4)(0.f);

  const int nsteps = Kpad / 32;
  for (int s = 0; s < nsteps; s++) {
    const int k0 = s * 32;
#pragma unroll
    for (int p = 0; p < 4; p++) {
      int e = p * 256 + tid;
      int r = e >> 3;
      int q4 = e & 7;
      int gr = row0 + r, gk = k0 + q4 * 4;
      float4 v = make_float4(0.f, 0.f, 0.f, 0.f);
      if (gr < M && gk < K) v = *(const float4*)&A[(long)gr * K + gk];
      unsigned short h0, h1, h2, h3, l0, l1, l2, l3;
      split_bf16(v.x, h0, l0);
      split_bf16(v.y, h1, l1);
      split_bf16(v.z, h2, l2);
      split_bf16(v.w, h3, l3);
      uint2 hh, ll;
      hh.x = (unsigned)h0 | ((unsigned)h1 << 16);
      hh.y = (unsigned)h2 | ((unsigned)h3 << 16);
      ll.x = (unsigned)l0 | ((unsigned)l1 << 16);
      ll.y = (unsigned)l2 | ((unsigned)l3 << 16);
      *(uint2*)&Ah[r * LDA + q4 * 4] = hh;
      *(uint2*)&Al[r * LDA + q4 * 4] = ll;
    }
#pragma unroll
    for (int p = 0; p < 2; p++) {
      int e = p * 256 + tid;
      int n = e & 127;
      int sel = e >> 7;
      const unsigned short* src = (sel & 2) ? Btl : Bth;
      unsigned short* dst = (sel & 2) ? Bl : Bh;
      int kk = (sel & 1) * 16;
      uint4 v0 = *(const uint4*)&src[(long)n * Kpad + k0 + kk];
      uint4 v1 = *(const uint4*)&src[(long)n * Kpad + k0 + kk + 8];
      *(uint4*)&dst[n * LDA + kk] = v0;
      *(uint4*)&dst[n * LDA + kk + 8] = v1;
    }
    __syncthreads();
    short8 afh[4], afl[4];
#pragma unroll
    for (int rt = 0; rt < 4; rt++) {
      int r = wr * 64 + rt * 16 + m16;
      afh[rt] = *(const short8*)&Ah[r * LDA + q * 8];
      afl[rt] = *(const short8*)&Al[r * LDA + q * 8];
    }
#pragma unroll
    for (int ct = 0; ct < 4; ct++) {
      int n = wc * 64 + ct * 16 + m16;
      short8 bfh = *(const short8*)&Bh[n * LDA + q * 8];
      short8 bfl = *(const short8*)&Bl[n * LDA + q * 8];
#pragma unroll
      for (int rt = 0; rt < 4; rt++) {
        acc[rt][ct] = __builtin_amdgcn_mfma_f32_16x16x32_bf16(afh[rt], bfh, acc[rt][ct], 0, 0, 0);
        acc[rt][ct] = __builtin_amdgcn_mfma_f32_16x16x32_bf16(afh[rt], bfl, acc[rt][ct], 0, 0, 0);
        acc[rt][ct] = __builtin_amdgcn_mfma_f32_16x16x32_bf16(afl[rt], bfh, acc[rt][ct], 0, 0, 0);
      }
    }
    __syncthreads();
  }

  float avs_r[4], avd_r[4];
#pragma unroll
  for (int ct = 0; ct < 4; ct++) {
    int n = wc * 64 + ct * 16 + m16;
    avs_r[ct] = avs[n];
    avd_r[ct] = avd[n];
  }
#pragma unroll
  for (int rt = 0; rt < 4; rt++) {
    int rbase = row0 + wr * 64 + rt * 16 + q * 4;
#pragma unroll
    for (int reg = 0; reg < 4; reg++) {
      int grow = rbase + reg;
      bool ok = grow < M;
      float ps = 0.f, pd = 0.f;
#pragma unroll
      for (int ct = 0; ct < 4; ct++) {
        float c = acc[rt][ct][reg];
        if (ok) C[(long)grow * 128 + wc * 64 + ct * 16 + m16] = f2bf_rne(c);
        ps = fmaf(c, avs_r[ct], ps);
        pd = fmaf(c, avd_r[ct], pd);
      }
#pragma unroll
      for (int d = 1; d < 16; d <<= 1) {
        ps += __shfl_xor(ps, d, 64);
        pd += __shfl_xor(pd, d, 64);
      }
      if (m16 == 0 && ok) {
        atomicAdd(&aS[grow], ps);
        atomicAdd(&aD[grow], pd);
      }
    }
  }
}

// ---------------- softmax attention + aggregation ----------------
// One block (128 thr) per dst. H is bf16. 4-way edge parallelism:
// edge-group eg = (wave<<1)|(lane>>5); lane owns features 4*(lane&31)..+3.

__global__ __launch_bounds__(128) void aggregate_kernel(const int* __restrict__ rowptr,
                                                        const int* __restrict__ colA,
                                                        const float* __restrict__ aS,
                                                        const float* __restrict__ aD,
                                                        const unsigned short* __restrict__ Hb,
                                                        const float* __restrict__ bias,
                                                        float* __restrict__ out,
                                                        int apply_gelu) {
  const int dst = blockIdx.x;
  const int tid = threadIdx.x;
  const int lane = tid & 63;
  const int w = tid >> 6;
  const int start = rowptr[dst];
  const int end = rowptr[dst + 1];
  const int deg = end - start;

  __shared__ int s_src[128];
  __shared__ float s_e[128];
  __shared__ float s_redA[2];
  __shared__ float s_redB[2];
  __shared__ float s_part[128];

  const float ad = aD[dst];
  float m = -__builtin_inff();
  float ssum = 0.f;

  for (int c0 = start; c0 < end; c0 += 128) {
    int i = c0 + tid;
    float e = -__builtin_inff();
    if (i < end) {
      int s = colA[i];
      float v = aS[s] + ad;
      e = (v > 0.f) ? v : 0.2f * v;
      s_src[tid] = s;
      s_e[tid] = e;
    }
    float cm = e;
#pragma unroll
    for (int d = 1; d < 64; d <<= 1) cm = fmaxf(cm, __shfl_xor(cm, d, 64));
    if (lane == 0) s_redA[w] = cm;
    __syncthreads();
    cm = fmaxf(s_redA[0], s_redA[1]);
    float ce = (i < end) ? expf(e - cm) : 0.f;
    float cs = ce;
#pragma unroll
    for (int d = 1; d < 64; d <<= 1) cs += __shfl_xor(cs, d, 64);
    if (lane == 0) s_redB[w] = cs;
    __syncthreads();
    cs = s_redB[0] + s_redB[1];
    float nm = fmaxf(m, cm);
    ssum = ssum * expf(m - nm) + cs * expf(cm - nm);
    m = nm;
  }

  const float inv = 1.f / ssum;
  const int eg = (w << 1) | ((lane >> 5) & 1);  // 0..3
  const int fl = lane & 31;                      // feature quad index
  float a0 = 0.f, a1 = 0.f, a2 = 0.f, a3 = 0.f;

  if (deg <= 128) {
    if (tid < deg) s_e[tid] = expf(s_e[tid] - m) * inv;
    __syncthreads();
    for (int i = 0; i < deg; i += 4) {
      int e = i + eg;
      if (e < deg) {
        float we = s_e[e];
        uint2 u = *(const uint2*)&Hb[(long)s_src[e] * DH + fl * 4];
        a0 = fmaf(we, __uint_as_float(u.x << 16), a0);
        a1 = fmaf(we, __uint_as_float(u.x & 0xFFFF0000u), a1);
        a2 = fmaf(we, __uint_as_float(u.y << 16), a2);
        a3 = fmaf(we, __uint_as_float(u.y & 0xFFFF0000u), a3);
      }
    }
  } else {
    for (int c0 = start; c0 < end; c0 += 128) {
      __syncthreads();
      int i = c0 + tid;
      if (i < end) {
        int s = colA[i];
        float v = aS[s] + ad;
        float e = (v > 0.f) ? v : 0.2f * v;
        s_src[tid] = s;
        s_e[tid] = expf(e - m) * inv;
      }
      __syncthreads();
      int lim = min(128, end - c0);
      for (int j = 0; j < lim; j += 4) {
        int e = j + eg;
        if (e < lim) {
          float we = s_e[e];
          uint2 u = *(const uint2*)&Hb[(long)s_src[e] * DH + fl * 4];
          a0 = fmaf(we, __uint_as_float(u.x << 16), a0);
          a1 = fmaf(we, __uint_as_float(u.x & 0xFFFF0000u), a1);
          a2 = fmaf(we, __uint_as_float(u.y << 16), a2);
          a3 = fmaf(we, __uint_as_float(u.y & 0xFFFF0000u), a3);
        }
      }
    }
  }

  // combine the two half-wave edge groups within each wave
  a0 += __shfl_xor(a0, 32, 64);
  a1 += __shfl_xor(a1, 32, 64);
  a2 += __shfl_xor(a2, 32, 64);
  a3 += __shfl_xor(a3, 32, 64);
  __syncthreads();  // s_e/s_src no longer needed
  if (w == 1 && lane < 32) {
    *(float4*)&s_part[fl * 4] = make_float4(a0, a1, a2, a3);
  }
  __syncthreads();
  if (w == 0 && lane < 32) {
    float4 p = *(const float4*)&s_part[fl * 4];
    float4 b = *(const float4*)&bias[fl * 4];
    float r0 = a0 + p.x + b.x;
    float r1 = a1 + p.y + b.y;
    float r2 = a2 + p.z + b.z;
    float r3 = a3 + p.w + b.w;
    if (apply_gelu) {
      r0 = gelu_exact(r0); r1 = gelu_exact(r1);
      r2 = gelu_exact(r2); r3 = gelu_exact(r3);
    }
    *(float4*)&out[(long)dst * DH + fl * 4] = make_float4(r0, r1, r2, r3);
  }
}

// ---------------- masked per-graph mean pooling (batch is sorted) ----------------

__global__ __launch_bounds__(128) void pool_kernel(const float* __restrict__ H,
                                                   const int* __restrict__ batch,
                                                   const int* __restrict__ pos,
                                                   float* __restrict__ sums,
                                                   float* __restrict__ cnt) {
  const int CH = 64;
  int n0 = blockIdx.x * CH;
  int n1 = min(n0 + CH, NN);
  int f = threadIdx.x;
  float acc = 0.f, c = 0.f;
  int g = batch[n0];
  for (int n = n0; n < n1; n++) {
    int gn = batch[n];
    if (gn != g) {
      atomicAdd(&sums[g * DH + f], acc);
      if (f == 0) atomicAdd(&cnt[g], c);
      acc = 0.f; c = 0.f; g = gn;
    }
    if (pos[n]) {
      acc += H[(long)n * DH + f];
      c += 1.f;
    }
  }
  atomicAdd(&sums[g * DH + f], acc);
  if (f == 0) atomicAdd(&cnt[g], c);
}

// ---------------- head ----------------

__global__ __launch_bounds__(128) void head_kernel(const float* __restrict__ sums,
                                                   const float* __restrict__ cnt,
                                                   const float* __restrict__ Wfc,
                                                   const float* __restrict__ bfc,
                                                   float* __restrict__ out) {
  int g = blockIdx.x;
  int f = threadIdx.x;
  float c = fmaxf(cnt[g], 1.f);
  float logit = sums[g * DH + f] / c;
  out[NG + g * DH + f] = logit;
  float gl = gelu_exact(logit) * Wfc[f];
  __shared__ float red[2];
#pragma unroll
  for (int d = 1; d < 64; d <<= 1) gl += __shfl_xor(gl, d, 64);
  int lane = f & 63, w = f >> 6;
  if (lane == 0) red[w] = gl;
  __syncthreads();
  if (f == 0) out[g] = red[0] + red[1] + bfc[0];
}

// ---------------- launch ----------------

extern "C" void kernel_launch(void* const* d_in, const int* in_sizes, int n_in,
                              void* d_out, int out_size, void* d_ws, size_t ws_size,
                              hipStream_t stream) {
  const float* x   = (const float*)d_in[0];
  const int* ei    = (const int*)d_in[1];
  const int* batch = (const int*)d_in[2];
  const int* pos   = (const int*)d_in[3];
  const float* W1  = (const float*)d_in[5];
  const float* as1 = (const float*)d_in[6];
  const float* ad1 = (const float*)d_in[7];
  const float* b1  = (const float*)d_in[8];
  const float* W2  = (const float*)d_in[9];
  const float* as2 = (const float*)d_in[10];
  const float* ad2 = (const float*)d_in[11];
  const float* b2  = (const float*)d_in[12];
  const float* Wfc = (const float*)d_in[13];
  const float* bfc = (const float*)d_in[14];
  float* out = (float*)d_out;

  const int KP1 = 320;
  const int KP2 = 128;

  char* ws = (char*)d_ws;
  size_t off = 0;
  auto nxt = [&](size_t b) -> void* {
    size_t p = off;
    off += (b + 255) & ~(size_t)255;
    return (void*)(ws + p);
  };
  int* rowptr = (int*)nxt((NN + 1) * sizeof(int));
  int* cursor = (int*)nxt(NN * sizeof(int));
  int* colA   = (int*)nxt((size_t)(EE + NN) * sizeof(int));
  float* aS   = (float*)nxt((size_t)2 * NN * sizeof(float));
  float* aD   = aS + NN;
  unsigned short* bufAb = (unsigned short*)nxt((size_t)NN * DH * sizeof(short));
  float* bufB = (float*)nxt((size_t)NN * DH * sizeof(float));
  float* sums = (float*)nxt((size_t)(NG * DH + NG) * sizeof(float));
  float* cnt  = sums + NG * DH;
  unsigned short* Bt1h = (unsigned short*)nxt((size_t)128 * KP1 * sizeof(short));
  unsigned short* Bt1l = (unsigned short*)nxt((size_t)128 * KP1 * sizeof(short));
  unsigned short* Bt2h = (unsigned short*)nxt((size_t)128 * KP2 * sizeof(short));
  unsigned short* Bt2l = (unsigned short*)nxt((size_t)128 * KP2 * sizeof(short));

  hipMemsetAsync(cursor, 0, NN * sizeof(int), stream);
  hipMemsetAsync(sums, 0, (NG * DH + NG) * sizeof(float), stream);
  hipMemsetAsync(aS, 0, (size_t)2 * NN * sizeof(float), stream);

  convert_bt_kernel<<<(128 * KP1 + 255) / 256, 256, 0, stream>>>(W1, Bt1h, Bt1l, DIN, KP1);
  convert_bt_kernel<<<(128 * KP2 + 255) / 256, 256, 0, stream>>>(W2, Bt2h, Bt2l, DH, KP2);

  const int eb = (EE + NN + 255) / 256;
  count_deg_kernel<<<eb, 256, 0, stream>>>(ei, cursor);
  scan_kernel<<<1, 1024, 0, stream>>>(cursor, rowptr);
  hipMemcpyAsync(cursor, rowptr, NN * sizeof(int), hipMemcpyDeviceToDevice, stream);
  scatter_kernel<<<eb, 256, 0, stream>>>(ei, cursor, colA);

  const int gblocks = (NN + 127) / 128;
  // layer 1
  gemm_mfma_kernel<<<gblocks, 256, 0, stream>>>(x, Bt1h, Bt1l, bufAb, NN, DIN, KP1,
                                                as1, ad1, aS, aD);
  aggregate_kernel<<<NN, 128, 0, stream>>>(rowptr, colA, aS, aD, bufAb, b1, bufB, 1);
  // layer 2
  hipMemsetAsync(aS, 0, (size_t)2 * NN * sizeof(float), stream);
  gemm_mfma_kernel<<<gblocks, 256, 0, stream>>>(bufB, Bt2h, Bt2l, bufAb, NN, DH, KP2,
                                                as2, ad2, aS, aD);
  aggregate_kernel<<<NN, 128, 0, stream>>>(rowptr, colA, aS, aD, bufAb, b2, bufB, 0);
  // pooling + head
  pool_kernel<<<(NN + 63) / 64, 128, 0, stream>>>(bufB, batch, pos, sums, cnt);
  head_kernel<<<NG, 128, 0, stream>>>(sums, cnt, Wfc, bfc, out);
}

// Round 5
// 417.998 us; speedup vs baseline: 1.6028x; 1.1291x over previous
//
#include <hip/hip_runtime.h>
#include <math.h>

#define NN 50000
#define EE 800000
#define DIN 300
#define DH 128
#define NG 128
#define LDA 40  // LDS row stride in bf16 units (pad 32 -> 40: conflict-free b128)

typedef __attribute__((ext_vector_type(8))) short short8;
typedef __attribute__((ext_vector_type(4))) float floatx4;

__device__ __forceinline__ float gelu_exact(float x) {
  return 0.5f * x * (1.0f + erff(x * 0.7071067811865476f));
}

__device__ __forceinline__ void split_bf16(float v, unsigned short& hi, unsigned short& lo) {
  unsigned int u = __float_as_uint(v);
  hi = (unsigned short)(u >> 16);
  float fh = __uint_as_float((unsigned int)hi << 16);
  lo = (unsigned short)(__float_as_uint(v - fh) >> 16);
}

__device__ __forceinline__ unsigned short f2bf_rne(float x) {
  unsigned int u = __float_as_uint(x);
  unsigned int r = (u + 0x7FFFu + ((u >> 16) & 1u)) >> 16;
  return (unsigned short)r;
}

__device__ __forceinline__ float readlane_f(float v, int l) {
  return __int_as_float(__builtin_amdgcn_readlane(__float_as_int(v), l));
}

// ---------------- CSR build ----------------

__global__ __launch_bounds__(256) void count_deg_kernel(const int* __restrict__ ei,
                                                        int* __restrict__ deg) {
  int e = blockIdx.x * 256 + threadIdx.x;
  if (e >= EE + NN) return;
  int d = (e < EE) ? ei[EE + e] : (e - EE);
  atomicAdd(&deg[d], 1);
}

// multi-block exclusive scan: part -> sums -> add
__global__ __launch_bounds__(1024) void scan_part_kernel(const int* __restrict__ deg,
                                                         int* __restrict__ rowptr,
                                                         int* __restrict__ bsum) {
  __shared__ int wsum[16];
  const int tid = threadIdx.x;
  const int lane = tid & 63;
  const int wid = tid >> 6;
  int idx = blockIdx.x * 1024 + tid;
  int v = (idx < NN) ? deg[idx] : 0;
  int x = v;
#pragma unroll
  for (int d = 1; d < 64; d <<= 1) {
    int y = __shfl_up(x, d, 64);
    if (lane >= d) x += y;
  }
  if (lane == 63) wsum[wid] = x;
  __syncthreads();
  if (wid == 0) {
    int s = (lane < 16) ? wsum[lane] : 0;
#pragma unroll
    for (int d = 1; d < 16; d <<= 1) {
      int y = __shfl_up(s, d, 64);
      if (lane >= d) s += y;
    }
    if (lane < 16) wsum[lane] = s;
  }
  __syncthreads();
  int woff = (wid > 0) ? wsum[wid - 1] : 0;
  int incl = x + woff;
  if (idx < NN) rowptr[idx] = incl - v;
  if (tid == 1023) bsum[blockIdx.x] = incl;
}

__global__ __launch_bounds__(64) void scan_sums_kernel(const int* __restrict__ bsum,
                                                       int* __restrict__ boff, int nb) {
  int lane = threadIdx.x;
  int v = (lane < nb) ? bsum[lane] : 0;
  int x = v;
#pragma unroll
  for (int d = 1; d < 64; d <<= 1) {
    int y = __shfl_up(x, d, 64);
    if (lane >= d) x += y;
  }
  if (lane < nb) boff[lane] = x - v;
  if (lane == nb - 1) boff[nb] = x;
}

__global__ __launch_bounds__(256) void scan_add_kernel(int* __restrict__ rowptr,
                                                       const int* __restrict__ boff,
                                                       int* __restrict__ cursor, int nb) {
  int i = blockIdx.x * 256 + threadIdx.x;
  if (i < NN) {
    int r = rowptr[i] + boff[i >> 10];
    rowptr[i] = r;
    cursor[i] = r;
  } else if (i == NN) {
    rowptr[NN] = boff[nb];
  }
}

__global__ __launch_bounds__(256) void scatter_kernel(const int* __restrict__ ei,
                                                      int* __restrict__ cursor,
                                                      int* __restrict__ colA) {
  int e = blockIdx.x * 256 + threadIdx.x;
  if (e >= EE + NN) return;
  int s, d;
  if (e < EE) { s = ei[e]; d = ei[EE + e]; }
  else        { s = e - EE; d = e - EE; }
  int p = atomicAdd(&cursor[d], 1);
  colA[p] = s;
}

// ---------------- B pre-transpose + split to bf16 hi/lo ----------------

__global__ __launch_bounds__(256) void convert_bt_kernel(const float* __restrict__ B,
                                                         unsigned short* __restrict__ Bth,
                                                         unsigned short* __restrict__ Btl,
                                                         int K, int Kpad) {
  int i = blockIdx.x * 256 + threadIdx.x;
  int n = i / Kpad, k = i % Kpad;
  if (n >= 128) return;
  float v = (k < K) ? B[(long)k * 128 + n] : 0.f;
  unsigned short h, l;
  split_bf16(v, h, l);
  Bth[(long)n * Kpad + k] = h;
  Btl[(long)n * Kpad + k] = l;
}

// ---------------- MFMA split-bf16 GEMM + fused attention row-dots ----------------
// C (bf16) [M,128] = A[M,K] @ B[K,128]; BM=64, BN=128, BK=32.
// 4 waves in 2x2; each wave 2x4 tiles of 16x16.

__global__ __launch_bounds__(256) void gemm_mfma_kernel(
    const float* __restrict__ A,
    const unsigned short* __restrict__ Bth, const unsigned short* __restrict__ Btl,
    unsigned short* __restrict__ C, int M, int K, int Kpad,
    const float* __restrict__ avs, const float* __restrict__ avd,
    float* __restrict__ aS, float* __restrict__ aD) {
  __shared__ unsigned short Ah[64 * LDA];
  __shared__ unsigned short Al[64 * LDA];
  __shared__ unsigned short Bh[128 * LDA];
  __shared__ unsigned short Bl[128 * LDA];

  const int tid = threadIdx.x;
  const int lane = tid & 63;
  const int w = tid >> 6;
  const int wr = w >> 1, wc = w & 1;
  const int q = lane >> 4;
  const int m16 = lane & 15;
  const int row0 = blockIdx.x * 64;

  floatx4 acc[2][4];
#pragma unroll
  for (int i = 0; i < 2; i++)
#pragma unroll
    for (int j = 0; j < 4; j++) acc[i][j] = (floatx4)(0.f);

  const int nsteps = Kpad / 32;
  for (int s = 0; s < nsteps; s++) {
    const int k0 = s * 32;
    // stage A: 64 rows x 32 k (fp32 -> hi/lo bf16)
#pragma unroll
    for (int p = 0; p < 2; p++) {
      int e = p * 256 + tid;   // 0..511
      int r = e >> 3;          // 0..63
      int q4 = e & 7;
      int gr = row0 + r, gk = k0 + q4 * 4;
      float4 v = make_float4(0.f, 0.f, 0.f, 0.f);
      if (gr < M && gk < K) v = *(const float4*)&A[(long)gr * K + gk];
      unsigned short h0, h1, h2, h3, l0, l1, l2, l3;
      split_bf16(v.x, h0, l0);
      split_bf16(v.y, h1, l1);
      split_bf16(v.z, h2, l2);
      split_bf16(v.w, h3, l3);
      uint2 hh, ll;
      hh.x = (unsigned)h0 | ((unsigned)h1 << 16);
      hh.y = (unsigned)h2 | ((unsigned)h3 << 16);
      ll.x = (unsigned)l0 | ((unsigned)l1 << 16);
      ll.y = (unsigned)l2 | ((unsigned)l3 << 16);
      *(uint2*)&Ah[r * LDA + q4 * 4] = hh;
      *(uint2*)&Al[r * LDA + q4 * 4] = ll;
    }
    // stage B: 128 cols x 32 k from pre-split Bt
#pragma unroll
    for (int p = 0; p < 2; p++) {
      int e = p * 256 + tid;   // 0..511
      int n = e & 127;
      int sel = e >> 7;
      const unsigned short* src = (sel & 2) ? Btl : Bth;
      unsigned short* dst = (sel & 2) ? Bl : Bh;
      int kk = (sel & 1) * 16;
      uint4 v0 = *(const uint4*)&src[(long)n * Kpad + k0 + kk];
      uint4 v1 = *(const uint4*)&src[(long)n * Kpad + k0 + kk + 8];
      *(uint4*)&dst[n * LDA + kk] = v0;
      *(uint4*)&dst[n * LDA + kk + 8] = v1;
    }
    __syncthreads();
    short8 afh[2], afl[2];
#pragma unroll
    for (int rt = 0; rt < 2; rt++) {
      int r = wr * 32 + rt * 16 + m16;
      afh[rt] = *(const short8*)&Ah[r * LDA + q * 8];
      afl[rt] = *(const short8*)&Al[r * LDA + q * 8];
    }
#pragma unroll
    for (int ct = 0; ct < 4; ct++) {
      int n = wc * 64 + ct * 16 + m16;
      short8 bfh = *(const short8*)&Bh[n * LDA + q * 8];
      short8 bfl = *(const short8*)&Bl[n * LDA + q * 8];
#pragma unroll
      for (int rt = 0; rt < 2; rt++) {
        acc[rt][ct] = __builtin_amdgcn_mfma_f32_16x16x32_bf16(afh[rt], bfh, acc[rt][ct], 0, 0, 0);
        acc[rt][ct] = __builtin_amdgcn_mfma_f32_16x16x32_bf16(afh[rt], bfl, acc[rt][ct], 0, 0, 0);
        acc[rt][ct] = __builtin_amdgcn_mfma_f32_16x16x32_bf16(afl[rt], bfh, acc[rt][ct], 0, 0, 0);
      }
    }
    __syncthreads();
  }

  float avs_r[4], avd_r[4];
#pragma unroll
  for (int ct = 0; ct < 4; ct++) {
    int n = wc * 64 + ct * 16 + m16;
    avs_r[ct] = avs[n];
    avd_r[ct] = avd[n];
  }
#pragma unroll
  for (int rt = 0; rt < 2; rt++) {
    int rbase = row0 + wr * 32 + rt * 16 + q * 4;
#pragma unroll
    for (int reg = 0; reg < 4; reg++) {
      int grow = rbase + reg;
      bool ok = grow < M;
      float ps = 0.f, pd = 0.f;
#pragma unroll
      for (int ct = 0; ct < 4; ct++) {
        float c = acc[rt][ct][reg];
        if (ok) C[(long)grow * 128 + wc * 64 + ct * 16 + m16] = f2bf_rne(c);
        ps = fmaf(c, avs_r[ct], ps);
        pd = fmaf(c, avd_r[ct], pd);
      }
#pragma unroll
      for (int d = 1; d < 16; d <<= 1) {
        ps += __shfl_xor(ps, d, 64);
        pd += __shfl_xor(pd, d, 64);
      }
      if (m16 == 0 && ok) {
        atomicAdd(&aS[grow], ps);
        atomicAdd(&aD[grow], pd);
      }
    }
  }
}

// ---------------- softmax attention + aggregation: one WAVE per dst ----------------
// Block 256 thr = 4 waves = 4 dst. No __syncthreads. Lane owns 2 features.
// deg<=64 fast path: softmax entirely in wave shuffles; per-edge broadcast via readlane.

__global__ __launch_bounds__(256) void aggregate_kernel(const int* __restrict__ rowptr,
                                                        const int* __restrict__ colA,
                                                        const float* __restrict__ aS,
                                                        const float* __restrict__ aD,
                                                        const unsigned short* __restrict__ Hb,
                                                        const float* __restrict__ bias,
                                                        float* __restrict__ out,
                                                        int apply_gelu) {
  const int lane = threadIdx.x & 63;
  const int dst = blockIdx.x * 4 + (threadIdx.x >> 6);
  if (dst >= NN) return;
  const int start = rowptr[dst];
  const int end = rowptr[dst + 1];
  const int deg = end - start;
  const float ad = aD[dst];

  float acc0 = 0.f, acc1 = 0.f;

  if (deg <= 64) {
    int src = 0;
    float e = -__builtin_inff();
    if (lane < deg) {
      src = colA[start + lane];
      float v = aS[src] + ad;
      e = (v > 0.f) ? v : 0.2f * v;
    }
    float mx = e;
#pragma unroll
    for (int d = 1; d < 64; d <<= 1) mx = fmaxf(mx, __shfl_xor(mx, d, 64));
    float ew = (lane < deg) ? expf(e - mx) : 0.f;
    float ss = ew;
#pragma unroll
    for (int d = 1; d < 64; d <<= 1) ss += __shfl_xor(ss, d, 64);
    float wgt = ew * (1.f / ss);
    for (int j = 0; j < deg; j++) {
      int sj = __builtin_amdgcn_readlane(src, j);
      float wj = readlane_f(wgt, j);
      unsigned u = *(const unsigned*)&Hb[(long)sj * DH + lane * 2];
      acc0 = fmaf(wj, __uint_as_float(u << 16), acc0);
      acc1 = fmaf(wj, __uint_as_float(u & 0xFFFF0000u), acc1);
    }
  } else {
    // generic path (deg > 64): online softmax over 64-edge chunks, two passes
    float m = -__builtin_inff(), ssum = 0.f;
    for (int c0 = start; c0 < end; c0 += 64) {
      int i = c0 + lane;
      float e = -__builtin_inff();
      if (i < end) {
        int s = colA[i];
        float v = aS[s] + ad;
        e = (v > 0.f) ? v : 0.2f * v;
      }
      float cm = e;
#pragma unroll
      for (int d = 1; d < 64; d <<= 1) cm = fmaxf(cm, __shfl_xor(cm, d, 64));
      float ce = (i < end) ? expf(e - cm) : 0.f;
      float cs = ce;
#pragma unroll
      for (int d = 1; d < 64; d <<= 1) cs += __shfl_xor(cs, d, 64);
      float nm = fmaxf(m, cm);
      ssum = ssum * expf(m - nm) + cs * expf(cm - nm);
      m = nm;
    }
    float inv = 1.f / ssum;
    for (int c0 = start; c0 < end; c0 += 64) {
      int i = c0 + lane;
      int src = 0;
      float wgt = 0.f;
      if (i < end) {
        src = colA[i];
        float v = aS[src] + ad;
        float e = (v > 0.f) ? v : 0.2f * v;
        wgt = expf(e - m) * inv;
      }
      int lim = min(64, end - c0);
      for (int j = 0; j < lim; j++) {
        int sj = __builtin_amdgcn_readlane(src, j);
        float wj = readlane_f(wgt, j);
        unsigned u = *(const unsigned*)&Hb[(long)sj * DH + lane * 2];
        acc0 = fmaf(wj, __uint_as_float(u << 16), acc0);
        acc1 = fmaf(wj, __uint_as_float(u & 0xFFFF0000u), acc1);
      }
    }
  }

  float2 b = *(const float2*)&bias[lane * 2];
  float r0 = acc0 + b.x;
  float r1 = acc1 + b.y;
  if (apply_gelu) {
    r0 = gelu_exact(r0);
    r1 = gelu_exact(r1);
  }
  *(float2*)&out[(long)dst * DH + lane * 2] = make_float2(r0, r1);
}

// ---------------- masked per-graph mean pooling (batch is sorted) ----------------

__global__ __launch_bounds__(128) void pool_kernel(const float* __restrict__ H,
                                                   const int* __restrict__ batch,
                                                   const int* __restrict__ pos,
                                                   float* __restrict__ sums,
                                                   float* __restrict__ cnt) {
  const int CH = 64;
  int n0 = blockIdx.x * CH;
  int n1 = min(n0 + CH, NN);
  int f = threadIdx.x;
  float acc = 0.f, c = 0.f;
  int g = batch[n0];
  for (int n = n0; n < n1; n++) {
    int gn = batch[n];
    if (gn != g) {
      atomicAdd(&sums[g * DH + f], acc);
      if (f == 0) atomicAdd(&cnt[g], c);
      acc = 0.f; c = 0.f; g = gn;
    }
    if (pos[n]) {
      acc += H[(long)n * DH + f];
      c += 1.f;
    }
  }
  atomicAdd(&sums[g * DH + f], acc);
  if (f == 0) atomicAdd(&cnt[g], c);
}

// ---------------- head ----------------

__global__ __launch_bounds__(128) void head_kernel(const float* __restrict__ sums,
                                                   const float* __restrict__ cnt,
                                                   const float* __restrict__ Wfc,
                                                   const float* __restrict__ bfc,
                                                   float* __restrict__ out) {
  int g = blockIdx.x;
  int f = threadIdx.x;
  float c = fmaxf(cnt[g], 1.f);
  float logit = sums[g * DH + f] / c;
  out[NG + g * DH + f] = logit;
  float gl = gelu_exact(logit) * Wfc[f];
  __shared__ float red[2];
#pragma unroll
  for (int d = 1; d < 64; d <<= 1) gl += __shfl_xor(gl, d, 64);
  int lane = f & 63, w = f >> 6;
  if (lane == 0) red[w] = gl;
  __syncthreads();
  if (f == 0) out[g] = red[0] + red[1] + bfc[0];
}

// ---------------- launch ----------------

extern "C" void kernel_launch(void* const* d_in, const int* in_sizes, int n_in,
                              void* d_out, int out_size, void* d_ws, size_t ws_size,
                              hipStream_t stream) {
  const float* x   = (const float*)d_in[0];
  const int* ei    = (const int*)d_in[1];
  const int* batch = (const int*)d_in[2];
  const int* pos   = (const int*)d_in[3];
  const float* W1  = (const float*)d_in[5];
  const float* as1 = (const float*)d_in[6];
  const float* ad1 = (const float*)d_in[7];
  const float* b1  = (const float*)d_in[8];
  const float* W2  = (const float*)d_in[9];
  const float* as2 = (const float*)d_in[10];
  const float* ad2 = (const float*)d_in[11];
  const float* b2  = (const float*)d_in[12];
  const float* Wfc = (const float*)d_in[13];
  const float* bfc = (const float*)d_in[14];
  float* out = (float*)d_out;

  const int KP1 = 320;
  const int KP2 = 128;
  const int NB_SCAN = (NN + 1023) / 1024;  // 49

  char* ws = (char*)d_ws;
  size_t off = 0;
  auto nxt = [&](size_t b) -> void* {
    size_t p = off;
    off += (b + 255) & ~(size_t)255;
    return (void*)(ws + p);
  };
  int* rowptr = (int*)nxt((NN + 1) * sizeof(int));
  int* cursor = (int*)nxt(NN * sizeof(int));
  int* colA   = (int*)nxt((size_t)(EE + NN) * sizeof(int));
  int* bsum   = (int*)nxt((NB_SCAN + 1) * sizeof(int));
  int* boff   = (int*)nxt((NB_SCAN + 1) * sizeof(int));
  float* aS   = (float*)nxt((size_t)2 * NN * sizeof(float));
  float* aD   = aS + NN;
  unsigned short* bufAb = (unsigned short*)nxt((size_t)NN * DH * sizeof(short));
  float* bufB = (float*)nxt((size_t)NN * DH * sizeof(float));
  float* sums = (float*)nxt((size_t)(NG * DH + NG) * sizeof(float));
  float* cnt  = sums + NG * DH;
  unsigned short* Bt1h = (unsigned short*)nxt((size_t)128 * KP1 * sizeof(short));
  unsigned short* Bt1l = (unsigned short*)nxt((size_t)128 * KP1 * sizeof(short));
  unsigned short* Bt2h = (unsigned short*)nxt((size_t)128 * KP2 * sizeof(short));
  unsigned short* Bt2l = (unsigned short*)nxt((size_t)128 * KP2 * sizeof(short));

  hipMemsetAsync(cursor, 0, NN * sizeof(int), stream);
  hipMemsetAsync(sums, 0, (NG * DH + NG) * sizeof(float), stream);
  hipMemsetAsync(aS, 0, (size_t)2 * NN * sizeof(float), stream);

  convert_bt_kernel<<<(128 * KP1 + 255) / 256, 256, 0, stream>>>(W1, Bt1h, Bt1l, DIN, KP1);
  convert_bt_kernel<<<(128 * KP2 + 255) / 256, 256, 0, stream>>>(W2, Bt2h, Bt2l, DH, KP2);

  const int eb = (EE + NN + 255) / 256;
  count_deg_kernel<<<eb, 256, 0, stream>>>(ei, cursor);
  scan_part_kernel<<<NB_SCAN, 1024, 0, stream>>>(cursor, rowptr, bsum);
  scan_sums_kernel<<<1, 64, 0, stream>>>(bsum, boff, NB_SCAN);
  scan_add_kernel<<<(NN + 1 + 255) / 256, 256, 0, stream>>>(rowptr, boff, cursor, NB_SCAN);
  scatter_kernel<<<eb, 256, 0, stream>>>(ei, cursor, colA);

  const int gblocks = (NN + 63) / 64;
  // layer 1
  gemm_mfma_kernel<<<gblocks, 256, 0, stream>>>(x, Bt1h, Bt1l, bufAb, NN, DIN, KP1,
                                                as1, ad1, aS, aD);
  aggregate_kernel<<<(NN + 3) / 4, 256, 0, stream>>>(rowptr, colA, aS, aD, bufAb, b1, bufB, 1);
  // layer 2
  hipMemsetAsync(aS, 0, (size_t)2 * NN * sizeof(float), stream);
  gemm_mfma_kernel<<<gblocks, 256, 0, stream>>>(bufB, Bt2h, Bt2l, bufAb, NN, DH, KP2,
                                                as2, ad2, aS, aD);
  aggregate_kernel<<<(NN + 3) / 4, 256, 0, stream>>>(rowptr, colA, aS, aD, bufAb, b2, bufB, 0);
  // pooling + head
  pool_kernel<<<(NN + 63) / 64, 128, 0, stream>>>(bufB, batch, pos, sums, cnt);
  head_kernel<<<NG, 128, 0, stream>>>(sums, cnt, Wfc, bfc, out);
}

// Round 6
// 375.663 us; speedup vs baseline: 1.7834x; 1.1127x over previous
//
#include <hip/hip_runtime.h>
#include <math.h>

#define NN 50000
#define EE 800000
#define DIN 300
#define DH 128
#define NG 128
#define LDA 40  // LDS row stride in bf16 units (pad 32 -> 40: conflict-free b128)

typedef __attribute__((ext_vector_type(8))) short short8;
typedef __attribute__((ext_vector_type(4))) float floatx4;

__device__ __forceinline__ float gelu_exact(float x) {
  return 0.5f * x * (1.0f + erff(x * 0.7071067811865476f));
}

__device__ __forceinline__ void split_bf16(float v, unsigned short& hi, unsigned short& lo) {
  unsigned int u = __float_as_uint(v);
  hi = (unsigned short)(u >> 16);
  float fh = __uint_as_float((unsigned int)hi << 16);
  lo = (unsigned short)(__float_as_uint(v - fh) >> 16);
}

__device__ __forceinline__ unsigned short f2bf_rne(float x) {
  unsigned int u = __float_as_uint(x);
  unsigned int r = (u + 0x7FFFu + ((u >> 16) & 1u)) >> 16;
  return (unsigned short)r;
}

__device__ __forceinline__ float bf_lo(unsigned u) { return __uint_as_float(u << 16); }
__device__ __forceinline__ float bf_hi(unsigned u) { return __uint_as_float(u & 0xFFFF0000u); }

// ---------------- CSR build ----------------

__global__ __launch_bounds__(256) void count_deg_kernel(const int* __restrict__ ei,
                                                        int* __restrict__ deg) {
  int e = blockIdx.x * 256 + threadIdx.x;
  if (e >= EE + NN) return;
  int d = (e < EE) ? ei[EE + e] : (e - EE);
  atomicAdd(&deg[d], 1);
}

// multi-block exclusive scan: part -> sums -> add
__global__ __launch_bounds__(1024) void scan_part_kernel(const int* __restrict__ deg,
                                                         int* __restrict__ rowptr,
                                                         int* __restrict__ bsum) {
  __shared__ int wsum[16];
  const int tid = threadIdx.x;
  const int lane = tid & 63;
  const int wid = tid >> 6;
  int idx = blockIdx.x * 1024 + tid;
  int v = (idx < NN) ? deg[idx] : 0;
  int x = v;
#pragma unroll
  for (int d = 1; d < 64; d <<= 1) {
    int y = __shfl_up(x, d, 64);
    if (lane >= d) x += y;
  }
  if (lane == 63) wsum[wid] = x;
  __syncthreads();
  if (wid == 0) {
    int s = (lane < 16) ? wsum[lane] : 0;
#pragma unroll
    for (int d = 1; d < 16; d <<= 1) {
      int y = __shfl_up(s, d, 64);
      if (lane >= d) s += y;
    }
    if (lane < 16) wsum[lane] = s;
  }
  __syncthreads();
  int woff = (wid > 0) ? wsum[wid - 1] : 0;
  int incl = x + woff;
  if (idx < NN) rowptr[idx] = incl - v;
  if (tid == 1023) bsum[blockIdx.x] = incl;
}

__global__ __launch_bounds__(64) void scan_sums_kernel(const int* __restrict__ bsum,
                                                       int* __restrict__ boff, int nb) {
  int lane = threadIdx.x;
  int v = (lane < nb) ? bsum[lane] : 0;
  int x = v;
#pragma unroll
  for (int d = 1; d < 64; d <<= 1) {
    int y = __shfl_up(x, d, 64);
    if (lane >= d) x += y;
  }
  if (lane < nb) boff[lane] = x - v;
  if (lane == nb - 1) boff[nb] = x;
}

__global__ __launch_bounds__(256) void scan_add_kernel(int* __restrict__ rowptr,
                                                       const int* __restrict__ boff,
                                                       int* __restrict__ cursor, int nb) {
  int i = blockIdx.x * 256 + threadIdx.x;
  if (i < NN) {
    int r = rowptr[i] + boff[i >> 10];
    rowptr[i] = r;
    cursor[i] = r;
  } else if (i == NN) {
    rowptr[NN] = boff[nb];
  }
}

__global__ __launch_bounds__(256) void scatter_kernel(const int* __restrict__ ei,
                                                      int* __restrict__ cursor,
                                                      int* __restrict__ colA) {
  int e = blockIdx.x * 256 + threadIdx.x;
  if (e >= EE + NN) return;
  int s, d;
  if (e < EE) { s = ei[e]; d = ei[EE + e]; }
  else        { s = e - EE; d = e - EE; }
  int p = atomicAdd(&cursor[d], 1);
  colA[p] = s;
}

// ---------------- B pre-transpose + split to bf16 hi/lo ----------------

__global__ __launch_bounds__(256) void convert_bt_kernel(const float* __restrict__ B,
                                                         unsigned short* __restrict__ Bth,
                                                         unsigned short* __restrict__ Btl,
                                                         int K, int Kpad) {
  int i = blockIdx.x * 256 + threadIdx.x;
  int n = i / Kpad, k = i % Kpad;
  if (n >= 128) return;
  float v = (k < K) ? B[(long)k * 128 + n] : 0.f;
  unsigned short h, l;
  split_bf16(v, h, l);
  Bth[(long)n * Kpad + k] = h;
  Btl[(long)n * Kpad + k] = l;
}

// ---------------- MFMA split-bf16 GEMM + fused attention row-dots ----------------
// C (bf16) [M,128] = A[M,K] @ B[K,128]; BM=64, BN=128, BK=32.

__global__ __launch_bounds__(256) void gemm_mfma_kernel(
    const float* __restrict__ A,
    const unsigned short* __restrict__ Bth, const unsigned short* __restrict__ Btl,
    unsigned short* __restrict__ C, int M, int K, int Kpad,
    const float* __restrict__ avs, const float* __restrict__ avd,
    float* __restrict__ aS, float* __restrict__ aD) {
  __shared__ unsigned short Ah[64 * LDA];
  __shared__ unsigned short Al[64 * LDA];
  __shared__ unsigned short Bh[128 * LDA];
  __shared__ unsigned short Bl[128 * LDA];

  const int tid = threadIdx.x;
  const int lane = tid & 63;
  const int w = tid >> 6;
  const int wr = w >> 1, wc = w & 1;
  const int q = lane >> 4;
  const int m16 = lane & 15;
  const int row0 = blockIdx.x * 64;

  floatx4 acc[2][4];
#pragma unroll
  for (int i = 0; i < 2; i++)
#pragma unroll
    for (int j = 0; j < 4; j++) acc[i][j] = (floatx4)(0.f);

  const int nsteps = Kpad / 32;
  for (int s = 0; s < nsteps; s++) {
    const int k0 = s * 32;
#pragma unroll
    for (int p = 0; p < 2; p++) {
      int e = p * 256 + tid;
      int r = e >> 3;
      int q4 = e & 7;
      int gr = row0 + r, gk = k0 + q4 * 4;
      float4 v = make_float4(0.f, 0.f, 0.f, 0.f);
      if (gr < M && gk < K) v = *(const float4*)&A[(long)gr * K + gk];
      unsigned short h0, h1, h2, h3, l0, l1, l2, l3;
      split_bf16(v.x, h0, l0);
      split_bf16(v.y, h1, l1);
      split_bf16(v.z, h2, l2);
      split_bf16(v.w, h3, l3);
      uint2 hh, ll;
      hh.x = (unsigned)h0 | ((unsigned)h1 << 16);
      hh.y = (unsigned)h2 | ((unsigned)h3 << 16);
      ll.x = (unsigned)l0 | ((unsigned)l1 << 16);
      ll.y = (unsigned)l2 | ((unsigned)l3 << 16);
      *(uint2*)&Ah[r * LDA + q4 * 4] = hh;
      *(uint2*)&Al[r * LDA + q4 * 4] = ll;
    }
#pragma unroll
    for (int p = 0; p < 2; p++) {
      int e = p * 256 + tid;
      int n = e & 127;
      int sel = e >> 7;
      const unsigned short* src = (sel & 2) ? Btl : Bth;
      unsigned short* dst = (sel & 2) ? Bl : Bh;
      int kk = (sel & 1) * 16;
      uint4 v0 = *(const uint4*)&src[(long)n * Kpad + k0 + kk];
      uint4 v1 = *(const uint4*)&src[(long)n * Kpad + k0 + kk + 8];
      *(uint4*)&dst[n * LDA + kk] = v0;
      *(uint4*)&dst[n * LDA + kk + 8] = v1;
    }
    __syncthreads();
    short8 afh[2], afl[2];
#pragma unroll
    for (int rt = 0; rt < 2; rt++) {
      int r = wr * 32 + rt * 16 + m16;
      afh[rt] = *(const short8*)&Ah[r * LDA + q * 8];
      afl[rt] = *(const short8*)&Al[r * LDA + q * 8];
    }
#pragma unroll
    for (int ct = 0; ct < 4; ct++) {
      int n = wc * 64 + ct * 16 + m16;
      short8 bfh = *(const short8*)&Bh[n * LDA + q * 8];
      short8 bfl = *(const short8*)&Bl[n * LDA + q * 8];
#pragma unroll
      for (int rt = 0; rt < 2; rt++) {
        acc[rt][ct] = __builtin_amdgcn_mfma_f32_16x16x32_bf16(afh[rt], bfh, acc[rt][ct], 0, 0, 0);
        acc[rt][ct] = __builtin_amdgcn_mfma_f32_16x16x32_bf16(afh[rt], bfl, acc[rt][ct], 0, 0, 0);
        acc[rt][ct] = __builtin_amdgcn_mfma_f32_16x16x32_bf16(afl[rt], bfh, acc[rt][ct], 0, 0, 0);
      }
    }
    __syncthreads();
  }

  float avs_r[4], avd_r[4];
#pragma unroll
  for (int ct = 0; ct < 4; ct++) {
    int n = wc * 64 + ct * 16 + m16;
    avs_r[ct] = avs[n];
    avd_r[ct] = avd[n];
  }
#pragma unroll
  for (int rt = 0; rt < 2; rt++) {
    int rbase = row0 + wr * 32 + rt * 16 + q * 4;
#pragma unroll
    for (int reg = 0; reg < 4; reg++) {
      int grow = rbase + reg;
      bool ok = grow < M;
      float ps = 0.f, pd = 0.f;
#pragma unroll
      for (int ct = 0; ct < 4; ct++) {
        float c = acc[rt][ct][reg];
        if (ok) C[(long)grow * 128 + wc * 64 + ct * 16 + m16] = f2bf_rne(c);
        ps = fmaf(c, avs_r[ct], ps);
        pd = fmaf(c, avd_r[ct], pd);
      }
#pragma unroll
      for (int d = 1; d < 16; d <<= 1) {
        ps += __shfl_xor(ps, d, 64);
        pd += __shfl_xor(pd, d, 64);
      }
      if (m16 == 0 && ok) {
        atomicAdd(&aS[grow], ps);
        atomicAdd(&aD[grow], pd);
      }
    }
  }
}

// ---------------- softmax attention + aggregation: one WAVE per dst ----------------
// Half-wave owns one edge (32 lanes x uint2 = 256B row); 2-deep unroll =>
// 4 independent 8B gathers in flight per wave. No __syncthreads.

__global__ __launch_bounds__(256) void aggregate_kernel(const int* __restrict__ rowptr,
                                                        const int* __restrict__ colA,
                                                        const float* __restrict__ aS,
                                                        const float* __restrict__ aD,
                                                        const unsigned short* __restrict__ Hb,
                                                        const float* __restrict__ bias,
                                                        float* __restrict__ out,
                                                        int apply_gelu) {
  const int lane = threadIdx.x & 63;
  const int dst = blockIdx.x * 4 + (threadIdx.x >> 6);
  if (dst >= NN) return;
  const int start = rowptr[dst];
  const int end = rowptr[dst + 1];
  const int deg = end - start;
  const float ad = aD[dst];
  const int half = lane >> 5;
  const int fl = lane & 31;

  float a0 = 0.f, a1 = 0.f, a2 = 0.f, a3 = 0.f;

  if (deg <= 64) {
    int src = 0;
    float e = -__builtin_inff();
    if (lane < deg) {
      src = colA[start + lane];
      float v = aS[src] + ad;
      e = (v > 0.f) ? v : 0.2f * v;
    }
    float mx = e;
#pragma unroll
    for (int d = 1; d < 64; d <<= 1) mx = fmaxf(mx, __shfl_xor(mx, d, 64));
    float ew = (lane < deg) ? expf(e - mx) : 0.f;
    float ss = ew;
#pragma unroll
    for (int d = 1; d < 64; d <<= 1) ss += __shfl_xor(ss, d, 64);
    float wgt = ew * (1.f / ss);
    // max j in loop is 60 => j0,j1 <= 63: shfl indices never wrap; lanes >= deg carry wgt=0.
    for (int j = 0; j < deg; j += 4) {
      int j0 = j + half;
      int j1 = j + 2 + half;
      int sj0 = __shfl(src, j0, 64);
      float wj0 = __shfl(wgt, j0, 64);
      int sj1 = __shfl(src, j1, 64);
      float wj1 = __shfl(wgt, j1, 64);
      uint2 u0 = *(const uint2*)&Hb[(long)sj0 * DH + fl * 4];
      uint2 u1 = *(const uint2*)&Hb[(long)sj1 * DH + fl * 4];
      a0 = fmaf(wj0, bf_lo(u0.x), a0);
      a1 = fmaf(wj0, bf_hi(u0.x), a1);
      a2 = fmaf(wj0, bf_lo(u0.y), a2);
      a3 = fmaf(wj0, bf_hi(u0.y), a3);
      a0 = fmaf(wj1, bf_lo(u1.x), a0);
      a1 = fmaf(wj1, bf_hi(u1.x), a1);
      a2 = fmaf(wj1, bf_lo(u1.y), a2);
      a3 = fmaf(wj1, bf_hi(u1.y), a3);
    }
  } else {
    // generic path (deg > 64, practically never): online softmax, then chunked gather
    float m = -__builtin_inff(), ssum = 0.f;
    for (int c0 = start; c0 < end; c0 += 64) {
      int i = c0 + lane;
      float e = -__builtin_inff();
      if (i < end) {
        int s = colA[i];
        float v = aS[s] + ad;
        e = (v > 0.f) ? v : 0.2f * v;
      }
      float cm = e;
#pragma unroll
      for (int d = 1; d < 64; d <<= 1) cm = fmaxf(cm, __shfl_xor(cm, d, 64));
      float ce = (i < end) ? expf(e - cm) : 0.f;
      float cs = ce;
#pragma unroll
      for (int d = 1; d < 64; d <<= 1) cs += __shfl_xor(cs, d, 64);
      float nm = fmaxf(m, cm);
      ssum = ssum * expf(m - nm) + cs * expf(cm - nm);
      m = nm;
    }
    float inv = 1.f / ssum;
    for (int c0 = start; c0 < end; c0 += 64) {
      int i = c0 + lane;
      int src = 0;
      float wgt = 0.f;
      if (i < end) {
        src = colA[i];
        float v = aS[src] + ad;
        float e = (v > 0.f) ? v : 0.2f * v;
        wgt = expf(e - m) * inv;
      }
      int lim = min(64, end - c0);
      for (int j = 0; j < lim; j += 4) {
        int j0 = j + half;
        int j1 = j + 2 + half;
        int sj0 = __shfl(src, j0, 64);
        float wj0 = __shfl(wgt, j0, 64);
        int sj1 = __shfl(src, j1, 64);
        float wj1 = __shfl(wgt, j1, 64);
        uint2 u0 = *(const uint2*)&Hb[(long)sj0 * DH + fl * 4];
        uint2 u1 = *(const uint2*)&Hb[(long)sj1 * DH + fl * 4];
        a0 = fmaf(wj0, bf_lo(u0.x), a0);
        a1 = fmaf(wj0, bf_hi(u0.x), a1);
        a2 = fmaf(wj0, bf_lo(u0.y), a2);
        a3 = fmaf(wj0, bf_hi(u0.y), a3);
        a0 = fmaf(wj1, bf_lo(u1.x), a0);
        a1 = fmaf(wj1, bf_hi(u1.x), a1);
        a2 = fmaf(wj1, bf_lo(u1.y), a2);
        a3 = fmaf(wj1, bf_hi(u1.y), a3);
      }
    }
  }

  // combine the two half-wave partial sums
  a0 += __shfl_xor(a0, 32, 64);
  a1 += __shfl_xor(a1, 32, 64);
  a2 += __shfl_xor(a2, 32, 64);
  a3 += __shfl_xor(a3, 32, 64);

  if (half == 0) {
    float4 b = *(const float4*)&bias[fl * 4];
    float r0 = a0 + b.x;
    float r1 = a1 + b.y;
    float r2 = a2 + b.z;
    float r3 = a3 + b.w;
    if (apply_gelu) {
      r0 = gelu_exact(r0); r1 = gelu_exact(r1);
      r2 = gelu_exact(r2); r3 = gelu_exact(r3);
    }
    *(float4*)&out[(long)dst * DH + fl * 4] = make_float4(r0, r1, r2, r3);
  }
}

// ---------------- masked per-graph mean pooling (batch is sorted) ----------------

__global__ __launch_bounds__(128) void pool_kernel(const float* __restrict__ H,
                                                   const int* __restrict__ batch,
                                                   const int* __restrict__ pos,
                                                   float* __restrict__ sums,
                                                   float* __restrict__ cnt) {
  const int CH = 64;
  int n0 = blockIdx.x * CH;
  int n1 = min(n0 + CH, NN);
  int f = threadIdx.x;
  float acc = 0.f, c = 0.f;
  int g = batch[n0];
  for (int n = n0; n < n1; n++) {
    int gn = batch[n];
    if (gn != g) {
      atomicAdd(&sums[g * DH + f], acc);
      if (f == 0) atomicAdd(&cnt[g], c);
      acc = 0.f; c = 0.f; g = gn;
    }
    if (pos[n]) {
      acc += H[(long)n * DH + f];
      c += 1.f;
    }
  }
  atomicAdd(&sums[g * DH + f], acc);
  if (f == 0) atomicAdd(&cnt[g], c);
}

// ---------------- head ----------------

__global__ __launch_bounds__(128) void head_kernel(const float* __restrict__ sums,
                                                   const float* __restrict__ cnt,
                                                   const float* __restrict__ Wfc,
                                                   const float* __restrict__ bfc,
                                                   float* __restrict__ out) {
  int g = blockIdx.x;
  int f = threadIdx.x;
  float c = fmaxf(cnt[g], 1.f);
  float logit = sums[g * DH + f] / c;
  out[NG + g * DH + f] = logit;
  float gl = gelu_exact(logit) * Wfc[f];
  __shared__ float red[2];
#pragma unroll
  for (int d = 1; d < 64; d <<= 1) gl += __shfl_xor(gl, d, 64);
  int lane = f & 63, w = f >> 6;
  if (lane == 0) red[w] = gl;
  __syncthreads();
  if (f == 0) out[g] = red[0] + red[1] + bfc[0];
}

// ---------------- launch ----------------

extern "C" void kernel_launch(void* const* d_in, const int* in_sizes, int n_in,
                              void* d_out, int out_size, void* d_ws, size_t ws_size,
                              hipStream_t stream) {
  const float* x   = (const float*)d_in[0];
  const int* ei    = (const int*)d_in[1];
  const int* batch = (const int*)d_in[2];
  const int* pos   = (const int*)d_in[3];
  const float* W1  = (const float*)d_in[5];
  const float* as1 = (const float*)d_in[6];
  const float* ad1 = (const float*)d_in[7];
  const float* b1  = (const float*)d_in[8];
  const float* W2  = (const float*)d_in[9];
  const float* as2 = (const float*)d_in[10];
  const float* ad2 = (const float*)d_in[11];
  const float* b2  = (const float*)d_in[12];
  const float* Wfc = (const float*)d_in[13];
  const float* bfc = (const float*)d_in[14];
  float* out = (float*)d_out;

  const int KP1 = 320;
  const int KP2 = 128;
  const int NB_SCAN = (NN + 1023) / 1024;  // 49

  char* ws = (char*)d_ws;
  size_t off = 0;
  auto nxt = [&](size_t b) -> void* {
    size_t p = off;
    off += (b + 255) & ~(size_t)255;
    return (void*)(ws + p);
  };
  int* rowptr = (int*)nxt((NN + 1) * sizeof(int));
  int* cursor = (int*)nxt(NN * sizeof(int));
  int* colA   = (int*)nxt((size_t)(EE + NN) * sizeof(int));
  int* bsum   = (int*)nxt((NB_SCAN + 1) * sizeof(int));
  int* boff   = (int*)nxt((NB_SCAN + 1) * sizeof(int));
  float* aS   = (float*)nxt((size_t)2 * NN * sizeof(float));
  float* aD   = aS + NN;
  unsigned short* bufAb = (unsigned short*)nxt((size_t)NN * DH * sizeof(short));
  float* bufB = (float*)nxt((size_t)NN * DH * sizeof(float));
  float* sums = (float*)nxt((size_t)(NG * DH + NG) * sizeof(float));
  float* cnt  = sums + NG * DH;
  unsigned short* Bt1h = (unsigned short*)nxt((size_t)128 * KP1 * sizeof(short));
  unsigned short* Bt1l = (unsigned short*)nxt((size_t)128 * KP1 * sizeof(short));
  unsigned short* Bt2h = (unsigned short*)nxt((size_t)128 * KP2 * sizeof(short));
  unsigned short* Bt2l = (unsigned short*)nxt((size_t)128 * KP2 * sizeof(short));

  hipMemsetAsync(cursor, 0, NN * sizeof(int), stream);
  hipMemsetAsync(sums, 0, (NG * DH + NG) * sizeof(float), stream);
  hipMemsetAsync(aS, 0, (size_t)2 * NN * sizeof(float), stream);

  convert_bt_kernel<<<(128 * KP1 + 255) / 256, 256, 0, stream>>>(W1, Bt1h, Bt1l, DIN, KP1);
  convert_bt_kernel<<<(128 * KP2 + 255) / 256, 256, 0, stream>>>(W2, Bt2h, Bt2l, DH, KP2);

  const int eb = (EE + NN + 255) / 256;
  count_deg_kernel<<<eb, 256, 0, stream>>>(ei, cursor);
  scan_part_kernel<<<NB_SCAN, 1024, 0, stream>>>(cursor, rowptr, bsum);
  scan_sums_kernel<<<1, 64, 0, stream>>>(bsum, boff, NB_SCAN);
  scan_add_kernel<<<(NN + 1 + 255) / 256, 256, 0, stream>>>(rowptr, boff, cursor, NB_SCAN);
  scatter_kernel<<<eb, 256, 0, stream>>>(ei, cursor, colA);

  const int gblocks = (NN + 63) / 64;
  // layer 1
  gemm_mfma_kernel<<<gblocks, 256, 0, stream>>>(x, Bt1h, Bt1l, bufAb, NN, DIN, KP1,
                                                as1, ad1, aS, aD);
  aggregate_kernel<<<(NN + 3) / 4, 256, 0, stream>>>(rowptr, colA, aS, aD, bufAb, b1, bufB, 1);
  // layer 2
  hipMemsetAsync(aS, 0, (size_t)2 * NN * sizeof(float), stream);
  gemm_mfma_kernel<<<gblocks, 256, 0, stream>>>(bufB, Bt2h, Bt2l, bufAb, NN, DH, KP2,
                                                as2, ad2, aS, aD);
  aggregate_kernel<<<(NN + 3) / 4, 256, 0, stream>>>(rowptr, colA, aS, aD, bufAb, b2, bufB, 0);
  // pooling + head
  pool_kernel<<<(NN + 63) / 64, 128, 0, stream>>>(bufB, batch, pos, sums, cnt);
  head_kernel<<<NG, 128, 0, stream>>>(sums, cnt, Wfc, bfc, out);
}

// Round 7
// 366.356 us; speedup vs baseline: 1.8287x; 1.0254x over previous
//
#include <hip/hip_runtime.h>
#include <math.h>

#define NN 50000
#define EE 800000
#define DIN 300
#define DH 128
#define NG 128
#define LDA 40  // LDS row stride in bf16 units (pad 32 -> 40: conflict-free b128)
#define RSIZE 6250  // NN/8 dst-range per XCD partition

typedef __attribute__((ext_vector_type(8))) short short8;
typedef __attribute__((ext_vector_type(4))) float floatx4;

__device__ __forceinline__ float gelu_exact(float x) {
  return 0.5f * x * (1.0f + erff(x * 0.7071067811865476f));
}

__device__ __forceinline__ void split_bf16(float v, unsigned short& hi, unsigned short& lo) {
  unsigned int u = __float_as_uint(v);
  hi = (unsigned short)(u >> 16);
  float fh = __uint_as_float((unsigned int)hi << 16);
  lo = (unsigned short)(__float_as_uint(v - fh) >> 16);
}

__device__ __forceinline__ unsigned short f2bf_rne(float x) {
  unsigned int u = __float_as_uint(x);
  unsigned int r = (u + 0x7FFFu + ((u >> 16) & 1u)) >> 16;
  return (unsigned short)r;
}

__device__ __forceinline__ float bf_lo(unsigned u) { return __uint_as_float(u << 16); }
__device__ __forceinline__ float bf_hi(unsigned u) { return __uint_as_float(u & 0xFFFF0000u); }

// ---------------- CSR build (XCD-partitioned by dst range) ----------------
// blockIdx.x & 7 selects a dst range; with round-robin block->XCD dispatch each
// range's counters / colA slice stays exclusively dirty in ONE XCD's L2, so the
// random 4B atomic/store traffic write-combines instead of costing a 64B HBM
// line per store (was: WRITE_SIZE 54.8 MB for a 3.4 MB array).

__global__ __launch_bounds__(256) void count_part_kernel(const int* __restrict__ ei,
                                                         int* __restrict__ deg,
                                                         int blocksPerRange) {
  const int r = blockIdx.x & 7;
  const int t = blockIdx.x >> 3;
  const int lo = r * RSIZE, hi = lo + RSIZE;
  const int total = EE + NN;
  const int step = blocksPerRange * 256;
  for (int e0 = t * 256; e0 < total; e0 += step) {
    int e = e0 + threadIdx.x;
    if (e < total) {
      int d = (e < EE) ? ei[EE + e] : (e - EE);
      if (d >= lo && d < hi) atomicAdd(&deg[d], 1);
    }
  }
}

// multi-block exclusive scan: part -> sums -> add
__global__ __launch_bounds__(1024) void scan_part_kernel(const int* __restrict__ deg,
                                                         int* __restrict__ rowptr,
                                                         int* __restrict__ bsum) {
  __shared__ int wsum[16];
  const int tid = threadIdx.x;
  const int lane = tid & 63;
  const int wid = tid >> 6;
  int idx = blockIdx.x * 1024 + tid;
  int v = (idx < NN) ? deg[idx] : 0;
  int x = v;
#pragma unroll
  for (int d = 1; d < 64; d <<= 1) {
    int y = __shfl_up(x, d, 64);
    if (lane >= d) x += y;
  }
  if (lane == 63) wsum[wid] = x;
  __syncthreads();
  if (wid == 0) {
    int s = (lane < 16) ? wsum[lane] : 0;
#pragma unroll
    for (int d = 1; d < 16; d <<= 1) {
      int y = __shfl_up(s, d, 64);
      if (lane >= d) s += y;
    }
    if (lane < 16) wsum[lane] = s;
  }
  __syncthreads();
  int woff = (wid > 0) ? wsum[wid - 1] : 0;
  int incl = x + woff;
  if (idx < NN) rowptr[idx] = incl - v;
  if (tid == 1023) bsum[blockIdx.x] = incl;
}

__global__ __launch_bounds__(64) void scan_sums_kernel(const int* __restrict__ bsum,
                                                       int* __restrict__ boff, int nb) {
  int lane = threadIdx.x;
  int v = (lane < nb) ? bsum[lane] : 0;
  int x = v;
#pragma unroll
  for (int d = 1; d < 64; d <<= 1) {
    int y = __shfl_up(x, d, 64);
    if (lane >= d) x += y;
  }
  if (lane < nb) boff[lane] = x - v;
  if (lane == nb - 1) boff[nb] = x;
}

__global__ __launch_bounds__(256) void scan_add_kernel(int* __restrict__ rowptr,
                                                       const int* __restrict__ boff,
                                                       int* __restrict__ cursor, int nb) {
  int i = blockIdx.x * 256 + threadIdx.x;
  if (i < NN) {
    int r = rowptr[i] + boff[i >> 10];
    rowptr[i] = r;
    cursor[i] = r;
  } else if (i == NN) {
    rowptr[NN] = boff[nb];
  }
}

__global__ __launch_bounds__(256) void scatter_part_kernel(const int* __restrict__ ei,
                                                           int* __restrict__ cursor,
                                                           int* __restrict__ colA,
                                                           int blocksPerRange) {
  const int r = blockIdx.x & 7;
  const int t = blockIdx.x >> 3;
  const int lo = r * RSIZE, hi = lo + RSIZE;
  const int total = EE + NN;
  const int step = blocksPerRange * 256;
  for (int e0 = t * 256; e0 < total; e0 += step) {
    int e = e0 + threadIdx.x;
    if (e < total) {
      int d = (e < EE) ? ei[EE + e] : (e - EE);
      if (d >= lo && d < hi) {
        int s = (e < EE) ? ei[e] : d;
        int p = atomicAdd(&cursor[d], 1);
        colA[p] = s;
      }
    }
  }
}

// ---------------- B pre-transpose + split to bf16 hi/lo ----------------

__global__ __launch_bounds__(256) void convert_bt_kernel(const float* __restrict__ B,
                                                         unsigned short* __restrict__ Bth,
                                                         unsigned short* __restrict__ Btl,
                                                         int K, int Kpad) {
  int i = blockIdx.x * 256 + threadIdx.x;
  int n = i / Kpad, k = i % Kpad;
  if (n >= 128) return;
  float v = (k < K) ? B[(long)k * 128 + n] : 0.f;
  unsigned short h, l;
  split_bf16(v, h, l);
  Bth[(long)n * Kpad + k] = h;
  Btl[(long)n * Kpad + k] = l;
}

// ---------------- MFMA split-bf16 GEMM + fused attention row-dots ----------------
// C (bf16) [M,128] = A[M,K] @ B[K,128]; BM=64, BN=128, BK=32.

__global__ __launch_bounds__(256) void gemm_mfma_kernel(
    const float* __restrict__ A,
    const unsigned short* __restrict__ Bth, const unsigned short* __restrict__ Btl,
    unsigned short* __restrict__ C, int M, int K, int Kpad,
    const float* __restrict__ avs, const float* __restrict__ avd,
    float* __restrict__ aS, float* __restrict__ aD) {
  __shared__ unsigned short Ah[64 * LDA];
  __shared__ unsigned short Al[64 * LDA];
  __shared__ unsigned short Bh[128 * LDA];
  __shared__ unsigned short Bl[128 * LDA];

  const int tid = threadIdx.x;
  const int lane = tid & 63;
  const int w = tid >> 6;
  const int wr = w >> 1, wc = w & 1;
  const int q = lane >> 4;
  const int m16 = lane & 15;
  const int row0 = blockIdx.x * 64;

  floatx4 acc[2][4];
#pragma unroll
  for (int i = 0; i < 2; i++)
#pragma unroll
    for (int j = 0; j < 4; j++) acc[i][j] = (floatx4)(0.f);

  const int nsteps = Kpad / 32;
  for (int s = 0; s < nsteps; s++) {
    const int k0 = s * 32;
#pragma unroll
    for (int p = 0; p < 2; p++) {
      int e = p * 256 + tid;
      int r = e >> 3;
      int q4 = e & 7;
      int gr = row0 + r, gk = k0 + q4 * 4;
      float4 v = make_float4(0.f, 0.f, 0.f, 0.f);
      if (gr < M && gk < K) v = *(const float4*)&A[(long)gr * K + gk];
      unsigned short h0, h1, h2, h3, l0, l1, l2, l3;
      split_bf16(v.x, h0, l0);
      split_bf16(v.y, h1, l1);
      split_bf16(v.z, h2, l2);
      split_bf16(v.w, h3, l3);
      uint2 hh, ll;
      hh.x = (unsigned)h0 | ((unsigned)h1 << 16);
      hh.y = (unsigned)h2 | ((unsigned)h3 << 16);
      ll.x = (unsigned)l0 | ((unsigned)l1 << 16);
      ll.y = (unsigned)l2 | ((unsigned)l3 << 16);
      *(uint2*)&Ah[r * LDA + q4 * 4] = hh;
      *(uint2*)&Al[r * LDA + q4 * 4] = ll;
    }
#pragma unroll
    for (int p = 0; p < 2; p++) {
      int e = p * 256 + tid;
      int n = e & 127;
      int sel = e >> 7;
      const unsigned short* src = (sel & 2) ? Btl : Bth;
      unsigned short* dst = (sel & 2) ? Bl : Bh;
      int kk = (sel & 1) * 16;
      uint4 v0 = *(const uint4*)&src[(long)n * Kpad + k0 + kk];
      uint4 v1 = *(const uint4*)&src[(long)n * Kpad + k0 + kk + 8];
      *(uint4*)&dst[n * LDA + kk] = v0;
      *(uint4*)&dst[n * LDA + kk + 8] = v1;
    }
    __syncthreads();
    short8 afh[2], afl[2];
#pragma unroll
    for (int rt = 0; rt < 2; rt++) {
      int r = wr * 32 + rt * 16 + m16;
      afh[rt] = *(const short8*)&Ah[r * LDA + q * 8];
      afl[rt] = *(const short8*)&Al[r * LDA + q * 8];
    }
#pragma unroll
    for (int ct = 0; ct < 4; ct++) {
      int n = wc * 64 + ct * 16 + m16;
      short8 bfh = *(const short8*)&Bh[n * LDA + q * 8];
      short8 bfl = *(const short8*)&Bl[n * LDA + q * 8];
#pragma unroll
      for (int rt = 0; rt < 2; rt++) {
        acc[rt][ct] = __builtin_amdgcn_mfma_f32_16x16x32_bf16(afh[rt], bfh, acc[rt][ct], 0, 0, 0);
        acc[rt][ct] = __builtin_amdgcn_mfma_f32_16x16x32_bf16(afh[rt], bfl, acc[rt][ct], 0, 0, 0);
        acc[rt][ct] = __builtin_amdgcn_mfma_f32_16x16x32_bf16(afl[rt], bfh, acc[rt][ct], 0, 0, 0);
      }
    }
    __syncthreads();
  }

  float avs_r[4], avd_r[4];
#pragma unroll
  for (int ct = 0; ct < 4; ct++) {
    int n = wc * 64 + ct * 16 + m16;
    avs_r[ct] = avs[n];
    avd_r[ct] = avd[n];
  }
#pragma unroll
  for (int rt = 0; rt < 2; rt++) {
    int rbase = row0 + wr * 32 + rt * 16 + q * 4;
#pragma unroll
    for (int reg = 0; reg < 4; reg++) {
      int grow = rbase + reg;
      bool ok = grow < M;
      float ps = 0.f, pd = 0.f;
#pragma unroll
      for (int ct = 0; ct < 4; ct++) {
        float c = acc[rt][ct][reg];
        if (ok) C[(long)grow * 128 + wc * 64 + ct * 16 + m16] = f2bf_rne(c);
        ps = fmaf(c, avs_r[ct], ps);
        pd = fmaf(c, avd_r[ct], pd);
      }
#pragma unroll
      for (int d = 1; d < 16; d <<= 1) {
        ps += __shfl_xor(ps, d, 64);
        pd += __shfl_xor(pd, d, 64);
      }
      if (m16 == 0 && ok) {
        atomicAdd(&aS[grow], ps);
        atomicAdd(&aD[grow], pd);
      }
    }
  }
}

// ---------------- softmax attention + aggregation: one WAVE per dst ----------------

__global__ __launch_bounds__(256) void aggregate_kernel(const int* __restrict__ rowptr,
                                                        const int* __restrict__ colA,
                                                        const float* __restrict__ aS,
                                                        const float* __restrict__ aD,
                                                        const unsigned short* __restrict__ Hb,
                                                        const float* __restrict__ bias,
                                                        float* __restrict__ out,
                                                        int apply_gelu) {
  const int lane = threadIdx.x & 63;
  const int dst = blockIdx.x * 4 + (threadIdx.x >> 6);
  if (dst >= NN) return;
  const int start = rowptr[dst];
  const int end = rowptr[dst + 1];
  const int deg = end - start;
  const float ad = aD[dst];
  const int half = lane >> 5;
  const int fl = lane & 31;

  float a0 = 0.f, a1 = 0.f, a2 = 0.f, a3 = 0.f;

  if (deg <= 64) {
    int src = 0;
    float e = -__builtin_inff();
    if (lane < deg) {
      src = colA[start + lane];
      float v = aS[src] + ad;
      e = (v > 0.f) ? v : 0.2f * v;
    }
    float mx = e;
#pragma unroll
    for (int d = 1; d < 64; d <<= 1) mx = fmaxf(mx, __shfl_xor(mx, d, 64));
    float ew = (lane < deg) ? expf(e - mx) : 0.f;
    float ss = ew;
#pragma unroll
    for (int d = 1; d < 64; d <<= 1) ss += __shfl_xor(ss, d, 64);
    float wgt = ew * (1.f / ss);
    for (int j = 0; j < deg; j += 4) {
      int j0 = j + half;
      int j1 = j + 2 + half;
      int sj0 = __shfl(src, j0, 64);
      float wj0 = __shfl(wgt, j0, 64);
      int sj1 = __shfl(src, j1, 64);
      float wj1 = __shfl(wgt, j1, 64);
      uint2 u0 = *(const uint2*)&Hb[(long)sj0 * DH + fl * 4];
      uint2 u1 = *(const uint2*)&Hb[(long)sj1 * DH + fl * 4];
      a0 = fmaf(wj0, bf_lo(u0.x), a0);
      a1 = fmaf(wj0, bf_hi(u0.x), a1);
      a2 = fmaf(wj0, bf_lo(u0.y), a2);
      a3 = fmaf(wj0, bf_hi(u0.y), a3);
      a0 = fmaf(wj1, bf_lo(u1.x), a0);
      a1 = fmaf(wj1, bf_hi(u1.x), a1);
      a2 = fmaf(wj1, bf_lo(u1.y), a2);
      a3 = fmaf(wj1, bf_hi(u1.y), a3);
    }
  } else {
    float m = -__builtin_inff(), ssum = 0.f;
    for (int c0 = start; c0 < end; c0 += 64) {
      int i = c0 + lane;
      float e = -__builtin_inff();
      if (i < end) {
        int s = colA[i];
        float v = aS[s] + ad;
        e = (v > 0.f) ? v : 0.2f * v;
      }
      float cm = e;
#pragma unroll
      for (int d = 1; d < 64; d <<= 1) cm = fmaxf(cm, __shfl_xor(cm, d, 64));
      float ce = (i < end) ? expf(e - cm) : 0.f;
      float cs = ce;
#pragma unroll
      for (int d = 1; d < 64; d <<= 1) cs += __shfl_xor(cs, d, 64);
      float nm = fmaxf(m, cm);
      ssum = ssum * expf(m - nm) + cs * expf(cm - nm);
      m = nm;
    }
    float inv = 1.f / ssum;
    for (int c0 = start; c0 < end; c0 += 64) {
      int i = c0 + lane;
      int src = 0;
      float wgt = 0.f;
      if (i < end) {
        src = colA[i];
        float v = aS[src] + ad;
        float e = (v > 0.f) ? v : 0.2f * v;
        wgt = expf(e - m) * inv;
      }
      int lim = min(64, end - c0);
      for (int j = 0; j < lim; j += 4) {
        int j0 = j + half;
        int j1 = j + 2 + half;
        int sj0 = __shfl(src, j0, 64);
        float wj0 = __shfl(wgt, j0, 64);
        int sj1 = __shfl(src, j1, 64);
        float wj1 = __shfl(wgt, j1, 64);
        uint2 u0 = *(const uint2*)&Hb[(long)sj0 * DH + fl * 4];
        uint2 u1 = *(const uint2*)&Hb[(long)sj1 * DH + fl * 4];
        a0 = fmaf(wj0, bf_lo(u0.x), a0);
        a1 = fmaf(wj0, bf_hi(u0.x), a1);
        a2 = fmaf(wj0, bf_lo(u0.y), a2);
        a3 = fmaf(wj0, bf_hi(u0.y), a3);
        a0 = fmaf(wj1, bf_lo(u1.x), a0);
        a1 = fmaf(wj1, bf_hi(u1.x), a1);
        a2 = fmaf(wj1, bf_lo(u1.y), a2);
        a3 = fmaf(wj1, bf_hi(u1.y), a3);
      }
    }
  }

  a0 += __shfl_xor(a0, 32, 64);
  a1 += __shfl_xor(a1, 32, 64);
  a2 += __shfl_xor(a2, 32, 64);
  a3 += __shfl_xor(a3, 32, 64);

  if (half == 0) {
    float4 b = *(const float4*)&bias[fl * 4];
    float r0 = a0 + b.x;
    float r1 = a1 + b.y;
    float r2 = a2 + b.z;
    float r3 = a3 + b.w;
    if (apply_gelu) {
      r0 = gelu_exact(r0); r1 = gelu_exact(r1);
      r2 = gelu_exact(r2); r3 = gelu_exact(r3);
    }
    *(float4*)&out[(long)dst * DH + fl * 4] = make_float4(r0, r1, r2, r3);
  }
}

// ---------------- masked per-graph mean pooling (batch is sorted) ----------------

__global__ __launch_bounds__(128) void pool_kernel(const float* __restrict__ H,
                                                   const int* __restrict__ batch,
                                                   const int* __restrict__ pos,
                                                   float* __restrict__ sums,
                                                   float* __restrict__ cnt) {
  const int CH = 64;
  int n0 = blockIdx.x * CH;
  int n1 = min(n0 + CH, NN);
  int f = threadIdx.x;
  float acc = 0.f, c = 0.f;
  int g = batch[n0];
  for (int n = n0; n < n1; n++) {
    int gn = batch[n];
    if (gn != g) {
      atomicAdd(&sums[g * DH + f], acc);
      if (f == 0) atomicAdd(&cnt[g], c);
      acc = 0.f; c = 0.f; g = gn;
    }
    if (pos[n]) {
      acc += H[(long)n * DH + f];
      c += 1.f;
    }
  }
  atomicAdd(&sums[g * DH + f], acc);
  if (f == 0) atomicAdd(&cnt[g], c);
}

// ---------------- head ----------------

__global__ __launch_bounds__(128) void head_kernel(const float* __restrict__ sums,
                                                   const float* __restrict__ cnt,
                                                   const float* __restrict__ Wfc,
                                                   const float* __restrict__ bfc,
                                                   float* __restrict__ out) {
  int g = blockIdx.x;
  int f = threadIdx.x;
  float c = fmaxf(cnt[g], 1.f);
  float logit = sums[g * DH + f] / c;
  out[NG + g * DH + f] = logit;
  float gl = gelu_exact(logit) * Wfc[f];
  __shared__ float red[2];
#pragma unroll
  for (int d = 1; d < 64; d <<= 1) gl += __shfl_xor(gl, d, 64);
  int lane = f & 63, w = f >> 6;
  if (lane == 0) red[w] = gl;
  __syncthreads();
  if (f == 0) out[g] = red[0] + red[1] + bfc[0];
}

// ---------------- launch ----------------

extern "C" void kernel_launch(void* const* d_in, const int* in_sizes, int n_in,
                              void* d_out, int out_size, void* d_ws, size_t ws_size,
                              hipStream_t stream) {
  const float* x   = (const float*)d_in[0];
  const int* ei    = (const int*)d_in[1];
  const int* batch = (const int*)d_in[2];
  const int* pos   = (const int*)d_in[3];
  const float* W1  = (const float*)d_in[5];
  const float* as1 = (const float*)d_in[6];
  const float* ad1 = (const float*)d_in[7];
  const float* b1  = (const float*)d_in[8];
  const float* W2  = (const float*)d_in[9];
  const float* as2 = (const float*)d_in[10];
  const float* ad2 = (const float*)d_in[11];
  const float* b2  = (const float*)d_in[12];
  const float* Wfc = (const float*)d_in[13];
  const float* bfc = (const float*)d_in[14];
  float* out = (float*)d_out;

  const int KP1 = 320;
  const int KP2 = 128;
  const int NB_SCAN = (NN + 1023) / 1024;  // 49
  const int BPR = 416;                      // blocks per dst-range (x8 ranges = 3328 blocks)

  char* ws = (char*)d_ws;
  size_t off = 0;
  auto nxt = [&](size_t b) -> void* {
    size_t p = off;
    off += (b + 255) & ~(size_t)255;
    return (void*)(ws + p);
  };
  int* rowptr = (int*)nxt((NN + 1) * sizeof(int));
  int* cursor = (int*)nxt(NN * sizeof(int));
  int* colA   = (int*)nxt((size_t)(EE + NN) * sizeof(int));
  int* bsum   = (int*)nxt((NB_SCAN + 1) * sizeof(int));
  int* boff   = (int*)nxt((NB_SCAN + 1) * sizeof(int));
  float* aS   = (float*)nxt((size_t)2 * NN * sizeof(float));
  float* aD   = aS + NN;
  unsigned short* bufAb = (unsigned short*)nxt((size_t)NN * DH * sizeof(short));
  float* bufB = (float*)nxt((size_t)NN * DH * sizeof(float));
  float* sums = (float*)nxt((size_t)(NG * DH + NG) * sizeof(float));
  float* cnt  = sums + NG * DH;
  unsigned short* Bt1h = (unsigned short*)nxt((size_t)128 * KP1 * sizeof(short));
  unsigned short* Bt1l = (unsigned short*)nxt((size_t)128 * KP1 * sizeof(short));
  unsigned short* Bt2h = (unsigned short*)nxt((size_t)128 * KP2 * sizeof(short));
  unsigned short* Bt2l = (unsigned short*)nxt((size_t)128 * KP2 * sizeof(short));

  hipMemsetAsync(cursor, 0, NN * sizeof(int), stream);
  hipMemsetAsync(sums, 0, (NG * DH + NG) * sizeof(float), stream);
  hipMemsetAsync(aS, 0, (size_t)2 * NN * sizeof(float), stream);

  convert_bt_kernel<<<(128 * KP1 + 255) / 256, 256, 0, stream>>>(W1, Bt1h, Bt1l, DIN, KP1);
  convert_bt_kernel<<<(128 * KP2 + 255) / 256, 256, 0, stream>>>(W2, Bt2h, Bt2l, DH, KP2);

  count_part_kernel<<<8 * BPR, 256, 0, stream>>>(ei, cursor, BPR);
  scan_part_kernel<<<NB_SCAN, 1024, 0, stream>>>(cursor, rowptr, bsum);
  scan_sums_kernel<<<1, 64, 0, stream>>>(bsum, boff, NB_SCAN);
  scan_add_kernel<<<(NN + 1 + 255) / 256, 256, 0, stream>>>(rowptr, boff, cursor, NB_SCAN);
  scatter_part_kernel<<<8 * BPR, 256, 0, stream>>>(ei, cursor, colA, BPR);

  const int gblocks = (NN + 63) / 64;
  // layer 1
  gemm_mfma_kernel<<<gblocks, 256, 0, stream>>>(x, Bt1h, Bt1l, bufAb, NN, DIN, KP1,
                                                as1, ad1, aS, aD);
  aggregate_kernel<<<(NN + 3) / 4, 256, 0, stream>>>(rowptr, colA, aS, aD, bufAb, b1, bufB, 1);
  // layer 2
  hipMemsetAsync(aS, 0, (size_t)2 * NN * sizeof(float), stream);
  gemm_mfma_kernel<<<gblocks, 256, 0, stream>>>(bufB, Bt2h, Bt2l, bufAb, NN, DH, KP2,
                                                as2, ad2, aS, aD);
  aggregate_kernel<<<(NN + 3) / 4, 256, 0, stream>>>(rowptr, colA, aS, aD, bufAb, b2, bufB, 0);
  // pooling + head
  pool_kernel<<<(NN + 63) / 64, 128, 0, stream>>>(bufB, batch, pos, sums, cnt);
  head_kernel<<<NG, 128, 0, stream>>>(sums, cnt, Wfc, bfc, out);
}

// Round 8
// 364.670 us; speedup vs baseline: 1.8372x; 1.0046x over previous
//
#include <hip/hip_runtime.h>
#include <math.h>

#define NN 50000
#define EE 800000
#define DIN 300
#define DH 128
#define NG 128
#define LDA 40  // LDS row stride in bf16 units (pad 32 -> 40: conflict-free b128)
#define RSIZE 6250  // NN/8 dst-range per XCD partition

typedef __attribute__((ext_vector_type(8))) short short8;
typedef __attribute__((ext_vector_type(4))) float floatx4;

__device__ __forceinline__ float gelu_exact(float x) {
  return 0.5f * x * (1.0f + erff(x * 0.7071067811865476f));
}

__device__ __forceinline__ void split_bf16(float v, unsigned short& hi, unsigned short& lo) {
  unsigned int u = __float_as_uint(v);
  hi = (unsigned short)(u >> 16);
  float fh = __uint_as_float((unsigned int)hi << 16);
  lo = (unsigned short)(__float_as_uint(v - fh) >> 16);
}

__device__ __forceinline__ unsigned short f2bf_rne(float x) {
  unsigned int u = __float_as_uint(x);
  unsigned int r = (u + 0x7FFFu + ((u >> 16) & 1u)) >> 16;
  return (unsigned short)r;
}

__device__ __forceinline__ float bf_lo(unsigned u) { return __uint_as_float(u << 16); }
__device__ __forceinline__ float bf_hi(unsigned u) { return __uint_as_float(u & 0xFFFF0000u); }

// ---------------- CSR build (XCD-partitioned by dst range) ----------------

__global__ __launch_bounds__(256) void count_part_kernel(const int* __restrict__ ei,
                                                         int* __restrict__ deg,
                                                         int blocksPerRange) {
  const int r = blockIdx.x & 7;
  const int t = blockIdx.x >> 3;
  const int lo = r * RSIZE, hi = lo + RSIZE;
  const int total = EE + NN;
  const int step = blocksPerRange * 256;
  for (int e0 = t * 256; e0 < total; e0 += step) {
    int e = e0 + threadIdx.x;
    if (e < total) {
      int d = (e < EE) ? ei[EE + e] : (e - EE);
      if (d >= lo && d < hi) atomicAdd(&deg[d], 1);
    }
  }
}

// multi-block exclusive scan: part -> sums -> add
__global__ __launch_bounds__(1024) void scan_part_kernel(const int* __restrict__ deg,
                                                         int* __restrict__ rowptr,
                                                         int* __restrict__ bsum) {
  __shared__ int wsum[16];
  const int tid = threadIdx.x;
  const int lane = tid & 63;
  const int wid = tid >> 6;
  int idx = blockIdx.x * 1024 + tid;
  int v = (idx < NN) ? deg[idx] : 0;
  int x = v;
#pragma unroll
  for (int d = 1; d < 64; d <<= 1) {
    int y = __shfl_up(x, d, 64);
    if (lane >= d) x += y;
  }
  if (lane == 63) wsum[wid] = x;
  __syncthreads();
  if (wid == 0) {
    int s = (lane < 16) ? wsum[lane] : 0;
#pragma unroll
    for (int d = 1; d < 16; d <<= 1) {
      int y = __shfl_up(s, d, 64);
      if (lane >= d) s += y;
    }
    if (lane < 16) wsum[lane] = s;
  }
  __syncthreads();
  int woff = (wid > 0) ? wsum[wid - 1] : 0;
  int incl = x + woff;
  if (idx < NN) rowptr[idx] = incl - v;
  if (tid == 1023) bsum[blockIdx.x] = incl;
}

__global__ __launch_bounds__(64) void scan_sums_kernel(const int* __restrict__ bsum,
                                                       int* __restrict__ boff, int nb) {
  int lane = threadIdx.x;
  int v = (lane < nb) ? bsum[lane] : 0;
  int x = v;
#pragma unroll
  for (int d = 1; d < 64; d <<= 1) {
    int y = __shfl_up(x, d, 64);
    if (lane >= d) x += y;
  }
  if (lane < nb) boff[lane] = x - v;
  if (lane == nb - 1) boff[nb] = x;
}

__global__ __launch_bounds__(256) void scan_add_kernel(int* __restrict__ rowptr,
                                                       const int* __restrict__ boff,
                                                       int* __restrict__ cursor, int nb) {
  int i = blockIdx.x * 256 + threadIdx.x;
  if (i < NN) {
    int r = rowptr[i] + boff[i >> 10];
    rowptr[i] = r;
    cursor[i] = r;
  } else if (i == NN) {
    rowptr[NN] = boff[nb];
  }
}

__global__ __launch_bounds__(256) void scatter_part_kernel(const int* __restrict__ ei,
                                                           int* __restrict__ cursor,
                                                           int* __restrict__ colA,
                                                           int blocksPerRange) {
  const int r = blockIdx.x & 7;
  const int t = blockIdx.x >> 3;
  const int lo = r * RSIZE, hi = lo + RSIZE;
  const int total = EE + NN;
  const int step = blocksPerRange * 256;
  for (int e0 = t * 256; e0 < total; e0 += step) {
    int e = e0 + threadIdx.x;
    if (e < total) {
      int d = (e < EE) ? ei[EE + e] : (e - EE);
      if (d >= lo && d < hi) {
        int s = (e < EE) ? ei[e] : d;
        int p = atomicAdd(&cursor[d], 1);
        colA[p] = s;
      }
    }
  }
}

// ---------------- B pre-transpose + split to bf16 hi/lo ----------------

__global__ __launch_bounds__(256) void convert_bt_kernel(const float* __restrict__ B,
                                                         unsigned short* __restrict__ Bth,
                                                         unsigned short* __restrict__ Btl,
                                                         int K, int Kpad) {
  int i = blockIdx.x * 256 + threadIdx.x;
  int n = i / Kpad, k = i % Kpad;
  if (n >= 128) return;
  float v = (k < K) ? B[(long)k * 128 + n] : 0.f;
  unsigned short h, l;
  split_bf16(v, h, l);
  Bth[(long)n * Kpad + k] = h;
  Btl[(long)n * Kpad + k] = l;
}

// ---------------- MFMA split-bf16 GEMM + fused attention row-dots ----------------
// C (bf16) [M,128] = A[M,K] @ B[K,128]; BM=64, BN=128, BK=32.
// Software-pipelined: step s+1's global loads issued before step s's MFMAs,
// so the ~600cyc load latency hides behind compute instead of stalling the
// K-loop (was: MfmaUtil 8%, everything idle).

__global__ __launch_bounds__(256) void gemm_mfma_kernel(
    const float* __restrict__ A,
    const unsigned short* __restrict__ Bth, const unsigned short* __restrict__ Btl,
    unsigned short* __restrict__ C, int M, int K, int Kpad,
    const float* __restrict__ avs, const float* __restrict__ avd,
    float* __restrict__ aS, float* __restrict__ aD) {
  __shared__ unsigned short Ah[64 * LDA];
  __shared__ unsigned short Al[64 * LDA];
  __shared__ unsigned short Bh[128 * LDA];
  __shared__ unsigned short Bl[128 * LDA];

  const int tid = threadIdx.x;
  const int lane = tid & 63;
  const int w = tid >> 6;
  const int wr = w >> 1, wc = w & 1;
  const int q = lane >> 4;
  const int m16 = lane & 15;
  const int row0 = blockIdx.x * 64;

  // staging geometry (derived from tid; p in {0,1} folded into explicit regs)
  const int ar = tid >> 3;        // A row for p=0 (p=1: +32)
  const int aq4 = tid & 7;        // float4 index in 32-k chunk
  const int bn = tid & 127;       // B col
  const int bkk = (tid >> 7) * 16;  // B k-offset within chunk (p=0: Bth, p=1: Btl)

  floatx4 acc[2][4];
#pragma unroll
  for (int i = 0; i < 2; i++)
#pragma unroll
    for (int j = 0; j < 4; j++) acc[i][j] = (floatx4)(0.f);

  const int nsteps = Kpad / 32;

  float4 vA0, vA1;
  uint4 vB00, vB01, vB10, vB11;

  auto issue_loads = [&](int s) {
    const int k0 = s * 32;
    const int gk = k0 + aq4 * 4;
    int gr0 = row0 + ar;
    vA0 = make_float4(0.f, 0.f, 0.f, 0.f);
    vA1 = make_float4(0.f, 0.f, 0.f, 0.f);
    if (gk < K) {
      if (gr0 < M) vA0 = *(const float4*)&A[(long)gr0 * K + gk];
      if (gr0 + 32 < M) vA1 = *(const float4*)&A[(long)(gr0 + 32) * K + gk];
    }
    const long bb = (long)bn * Kpad + k0 + bkk;
    vB00 = *(const uint4*)&Bth[bb];
    vB01 = *(const uint4*)&Bth[bb + 8];
    vB10 = *(const uint4*)&Btl[bb];
    vB11 = *(const uint4*)&Btl[bb + 8];
  };

  auto write_stage = [&]() {
    unsigned short h0, h1, h2, h3, l0, l1, l2, l3;
    split_bf16(vA0.x, h0, l0);
    split_bf16(vA0.y, h1, l1);
    split_bf16(vA0.z, h2, l2);
    split_bf16(vA0.w, h3, l3);
    uint2 hh, ll;
    hh.x = (unsigned)h0 | ((unsigned)h1 << 16);
    hh.y = (unsigned)h2 | ((unsigned)h3 << 16);
    ll.x = (unsigned)l0 | ((unsigned)l1 << 16);
    ll.y = (unsigned)l2 | ((unsigned)l3 << 16);
    *(uint2*)&Ah[ar * LDA + aq4 * 4] = hh;
    *(uint2*)&Al[ar * LDA + aq4 * 4] = ll;
    split_bf16(vA1.x, h0, l0);
    split_bf16(vA1.y, h1, l1);
    split_bf16(vA1.z, h2, l2);
    split_bf16(vA1.w, h3, l3);
    hh.x = (unsigned)h0 | ((unsigned)h1 << 16);
    hh.y = (unsigned)h2 | ((unsigned)h3 << 16);
    ll.x = (unsigned)l0 | ((unsigned)l1 << 16);
    ll.y = (unsigned)l2 | ((unsigned)l3 << 16);
    *(uint2*)&Ah[(ar + 32) * LDA + aq4 * 4] = hh;
    *(uint2*)&Al[(ar + 32) * LDA + aq4 * 4] = ll;
    *(uint4*)&Bh[bn * LDA + bkk] = vB00;
    *(uint4*)&Bh[bn * LDA + bkk + 8] = vB01;
    *(uint4*)&Bl[bn * LDA + bkk] = vB10;
    *(uint4*)&Bl[bn * LDA + bkk + 8] = vB11;
  };

  issue_loads(0);
  for (int s = 0; s < nsteps; s++) {
    write_stage();
    __syncthreads();
    if (s + 1 < nsteps) issue_loads(s + 1);
    short8 afh[2], afl[2];
#pragma unroll
    for (int rt = 0; rt < 2; rt++) {
      int r = wr * 32 + rt * 16 + m16;
      afh[rt] = *(const short8*)&Ah[r * LDA + q * 8];
      afl[rt] = *(const short8*)&Al[r * LDA + q * 8];
    }
#pragma unroll
    for (int ct = 0; ct < 4; ct++) {
      int n = wc * 64 + ct * 16 + m16;
      short8 bfh = *(const short8*)&Bh[n * LDA + q * 8];
      short8 bfl = *(const short8*)&Bl[n * LDA + q * 8];
#pragma unroll
      for (int rt = 0; rt < 2; rt++) {
        acc[rt][ct] = __builtin_amdgcn_mfma_f32_16x16x32_bf16(afh[rt], bfh, acc[rt][ct], 0, 0, 0);
        acc[rt][ct] = __builtin_amdgcn_mfma_f32_16x16x32_bf16(afh[rt], bfl, acc[rt][ct], 0, 0, 0);
        acc[rt][ct] = __builtin_amdgcn_mfma_f32_16x16x32_bf16(afl[rt], bfh, acc[rt][ct], 0, 0, 0);
      }
    }
    __syncthreads();
  }

  float avs_r[4], avd_r[4];
#pragma unroll
  for (int ct = 0; ct < 4; ct++) {
    int n = wc * 64 + ct * 16 + m16;
    avs_r[ct] = avs[n];
    avd_r[ct] = avd[n];
  }
#pragma unroll
  for (int rt = 0; rt < 2; rt++) {
    int rbase = row0 + wr * 32 + rt * 16 + q * 4;
#pragma unroll
    for (int reg = 0; reg < 4; reg++) {
      int grow = rbase + reg;
      bool ok = grow < M;
      float ps = 0.f, pd = 0.f;
#pragma unroll
      for (int ct = 0; ct < 4; ct++) {
        float c = acc[rt][ct][reg];
        if (ok) C[(long)grow * 128 + wc * 64 + ct * 16 + m16] = f2bf_rne(c);
        ps = fmaf(c, avs_r[ct], ps);
        pd = fmaf(c, avd_r[ct], pd);
      }
#pragma unroll
      for (int d = 1; d < 16; d <<= 1) {
        ps += __shfl_xor(ps, d, 64);
        pd += __shfl_xor(pd, d, 64);
      }
      if (m16 == 0 && ok) {
        atomicAdd(&aS[grow], ps);
        atomicAdd(&aD[grow], pd);
      }
    }
  }
}

// ---------------- softmax attention + aggregation: one WAVE per dst ----------------

__global__ __launch_bounds__(256) void aggregate_kernel(const int* __restrict__ rowptr,
                                                        const int* __restrict__ colA,
                                                        const float* __restrict__ aS,
                                                        const float* __restrict__ aD,
                                                        const unsigned short* __restrict__ Hb,
                                                        const float* __restrict__ bias,
                                                        float* __restrict__ out,
                                                        int apply_gelu) {
  const int lane = threadIdx.x & 63;
  const int dst = blockIdx.x * 4 + (threadIdx.x >> 6);
  if (dst >= NN) return;
  const int start = rowptr[dst];
  const int end = rowptr[dst + 1];
  const int deg = end - start;
  const float ad = aD[dst];
  const int half = lane >> 5;
  const int fl = lane & 31;

  float a0 = 0.f, a1 = 0.f, a2 = 0.f, a3 = 0.f;

  if (deg <= 64) {
    int src = 0;
    float e = -__builtin_inff();
    if (lane < deg) {
      src = colA[start + lane];
      float v = aS[src] + ad;
      e = (v > 0.f) ? v : 0.2f * v;
    }
    float mx = e;
#pragma unroll
    for (int d = 1; d < 64; d <<= 1) mx = fmaxf(mx, __shfl_xor(mx, d, 64));
    float ew = (lane < deg) ? expf(e - mx) : 0.f;
    float ss = ew;
#pragma unroll
    for (int d = 1; d < 64; d <<= 1) ss += __shfl_xor(ss, d, 64);
    float wgt = ew * (1.f / ss);
    for (int j = 0; j < deg; j += 4) {
      int j0 = j + half;
      int j1 = j + 2 + half;
      int sj0 = __shfl(src, j0, 64);
      float wj0 = __shfl(wgt, j0, 64);
      int sj1 = __shfl(src, j1, 64);
      float wj1 = __shfl(wgt, j1, 64);
      uint2 u0 = *(const uint2*)&Hb[(long)sj0 * DH + fl * 4];
      uint2 u1 = *(const uint2*)&Hb[(long)sj1 * DH + fl * 4];
      a0 = fmaf(wj0, bf_lo(u0.x), a0);
      a1 = fmaf(wj0, bf_hi(u0.x), a1);
      a2 = fmaf(wj0, bf_lo(u0.y), a2);
      a3 = fmaf(wj0, bf_hi(u0.y), a3);
      a0 = fmaf(wj1, bf_lo(u1.x), a0);
      a1 = fmaf(wj1, bf_hi(u1.x), a1);
      a2 = fmaf(wj1, bf_lo(u1.y), a2);
      a3 = fmaf(wj1, bf_hi(u1.y), a3);
    }
  } else {
    float m = -__builtin_inff(), ssum = 0.f;
    for (int c0 = start; c0 < end; c0 += 64) {
      int i = c0 + lane;
      float e = -__builtin_inff();
      if (i < end) {
        int s = colA[i];
        float v = aS[s] + ad;
        e = (v > 0.f) ? v : 0.2f * v;
      }
      float cm = e;
#pragma unroll
      for (int d = 1; d < 64; d <<= 1) cm = fmaxf(cm, __shfl_xor(cm, d, 64));
      float ce = (i < end) ? expf(e - cm) : 0.f;
      float cs = ce;
#pragma unroll
      for (int d = 1; d < 64; d <<= 1) cs += __shfl_xor(cs, d, 64);
      float nm = fmaxf(m, cm);
      ssum = ssum * expf(m - nm) + cs * expf(cm - nm);
      m = nm;
    }
    float inv = 1.f / ssum;
    for (int c0 = start; c0 < end; c0 += 64) {
      int i = c0 + lane;
      int src = 0;
      float wgt = 0.f;
      if (i < end) {
        src = colA[i];
        float v = aS[src] + ad;
        float e = (v > 0.f) ? v : 0.2f * v;
        wgt = expf(e - m) * inv;
      }
      int lim = min(64, end - c0);
      for (int j = 0; j < lim; j += 4) {
        int j0 = j + half;
        int j1 = j + 2 + half;
        int sj0 = __shfl(src, j0, 64);
        float wj0 = __shfl(wgt, j0, 64);
        int sj1 = __shfl(src, j1, 64);
        float wj1 = __shfl(wgt, j1, 64);
        uint2 u0 = *(const uint2*)&Hb[(long)sj0 * DH + fl * 4];
        uint2 u1 = *(const uint2*)&Hb[(long)sj1 * DH + fl * 4];
        a0 = fmaf(wj0, bf_lo(u0.x), a0);
        a1 = fmaf(wj0, bf_hi(u0.x), a1);
        a2 = fmaf(wj0, bf_lo(u0.y), a2);
        a3 = fmaf(wj0, bf_hi(u0.y), a3);
        a0 = fmaf(wj1, bf_lo(u1.x), a0);
        a1 = fmaf(wj1, bf_hi(u1.x), a1);
        a2 = fmaf(wj1, bf_lo(u1.y), a2);
        a3 = fmaf(wj1, bf_hi(u1.y), a3);
      }
    }
  }

  a0 += __shfl_xor(a0, 32, 64);
  a1 += __shfl_xor(a1, 32, 64);
  a2 += __shfl_xor(a2, 32, 64);
  a3 += __shfl_xor(a3, 32, 64);

  if (half == 0) {
    float4 b = *(const float4*)&bias[fl * 4];
    float r0 = a0 + b.x;
    float r1 = a1 + b.y;
    float r2 = a2 + b.z;
    float r3 = a3 + b.w;
    if (apply_gelu) {
      r0 = gelu_exact(r0); r1 = gelu_exact(r1);
      r2 = gelu_exact(r2); r3 = gelu_exact(r3);
    }
    *(float4*)&out[(long)dst * DH + fl * 4] = make_float4(r0, r1, r2, r3);
  }
}

// ---------------- masked per-graph mean pooling (batch is sorted) ----------------

__global__ __launch_bounds__(128) void pool_kernel(const float* __restrict__ H,
                                                   const int* __restrict__ batch,
                                                   const int* __restrict__ pos,
                                                   float* __restrict__ sums,
                                                   float* __restrict__ cnt) {
  const int CH = 64;
  int n0 = blockIdx.x * CH;
  int n1 = min(n0 + CH, NN);
  int f = threadIdx.x;
  float acc = 0.f, c = 0.f;
  int g = batch[n0];
  for (int n = n0; n < n1; n++) {
    int gn = batch[n];
    if (gn != g) {
      atomicAdd(&sums[g * DH + f], acc);
      if (f == 0) atomicAdd(&cnt[g], c);
      acc = 0.f; c = 0.f; g = gn;
    }
    if (pos[n]) {
      acc += H[(long)n * DH + f];
      c += 1.f;
    }
  }
  atomicAdd(&sums[g * DH + f], acc);
  if (f == 0) atomicAdd(&cnt[g], c);
}

// ---------------- head ----------------

__global__ __launch_bounds__(128) void head_kernel(const float* __restrict__ sums,
                                                   const float* __restrict__ cnt,
                                                   const float* __restrict__ Wfc,
                                                   const float* __restrict__ bfc,
                                                   float* __restrict__ out) {
  int g = blockIdx.x;
  int f = threadIdx.x;
  float c = fmaxf(cnt[g], 1.f);
  float logit = sums[g * DH + f] / c;
  out[NG + g * DH + f] = logit;
  float gl = gelu_exact(logit) * Wfc[f];
  __shared__ float red[2];
#pragma unroll
  for (int d = 1; d < 64; d <<= 1) gl += __shfl_xor(gl, d, 64);
  int lane = f & 63, w = f >> 6;
  if (lane == 0) red[w] = gl;
  __syncthreads();
  if (f == 0) out[g] = red[0] + red[1] + bfc[0];
}

// ---------------- launch ----------------

extern "C" void kernel_launch(void* const* d_in, const int* in_sizes, int n_in,
                              void* d_out, int out_size, void* d_ws, size_t ws_size,
                              hipStream_t stream) {
  const float* x   = (const float*)d_in[0];
  const int* ei    = (const int*)d_in[1];
  const int* batch = (const int*)d_in[2];
  const int* pos   = (const int*)d_in[3];
  const float* W1  = (const float*)d_in[5];
  const float* as1 = (const float*)d_in[6];
  const float* ad1 = (const float*)d_in[7];
  const float* b1  = (const float*)d_in[8];
  const float* W2  = (const float*)d_in[9];
  const float* as2 = (const float*)d_in[10];
  const float* ad2 = (const float*)d_in[11];
  const float* b2  = (const float*)d_in[12];
  const float* Wfc = (const float*)d_in[13];
  const float* bfc = (const float*)d_in[14];
  float* out = (float*)d_out;

  const int KP1 = 320;
  const int KP2 = 128;
  const int NB_SCAN = (NN + 1023) / 1024;  // 49
  const int BPR = 416;                      // blocks per dst-range (x8 ranges)

  char* ws = (char*)d_ws;
  size_t off = 0;
  auto nxt = [&](size_t b) -> void* {
    size_t p = off;
    off += (b + 255) & ~(size_t)255;
    return (void*)(ws + p);
  };
  int* rowptr = (int*)nxt((NN + 1) * sizeof(int));
  int* cursor = (int*)nxt(NN * sizeof(int));
  int* colA   = (int*)nxt((size_t)(EE + NN) * sizeof(int));
  int* bsum   = (int*)nxt((NB_SCAN + 1) * sizeof(int));
  int* boff   = (int*)nxt((NB_SCAN + 1) * sizeof(int));
  float* aS   = (float*)nxt((size_t)2 * NN * sizeof(float));
  float* aD   = aS + NN;
  unsigned short* bufAb = (unsigned short*)nxt((size_t)NN * DH * sizeof(short));
  float* bufB = (float*)nxt((size_t)NN * DH * sizeof(float));
  float* sums = (float*)nxt((size_t)(NG * DH + NG) * sizeof(float));
  float* cnt  = sums + NG * DH;
  unsigned short* Bt1h = (unsigned short*)nxt((size_t)128 * KP1 * sizeof(short));
  unsigned short* Bt1l = (unsigned short*)nxt((size_t)128 * KP1 * sizeof(short));
  unsigned short* Bt2h = (unsigned short*)nxt((size_t)128 * KP2 * sizeof(short));
  unsigned short* Bt2l = (unsigned short*)nxt((size_t)128 * KP2 * sizeof(short));

  hipMemsetAsync(cursor, 0, NN * sizeof(int), stream);
  hipMemsetAsync(sums, 0, (NG * DH + NG) * sizeof(float), stream);
  hipMemsetAsync(aS, 0, (size_t)2 * NN * sizeof(float), stream);

  convert_bt_kernel<<<(128 * KP1 + 255) / 256, 256, 0, stream>>>(W1, Bt1h, Bt1l, DIN, KP1);
  convert_bt_kernel<<<(128 * KP2 + 255) / 256, 256, 0, stream>>>(W2, Bt2h, Bt2l, DH, KP2);

  count_part_kernel<<<8 * BPR, 256, 0, stream>>>(ei, cursor, BPR);
  scan_part_kernel<<<NB_SCAN, 1024, 0, stream>>>(cursor, rowptr, bsum);
  scan_sums_kernel<<<1, 64, 0, stream>>>(bsum, boff, NB_SCAN);
  scan_add_kernel<<<(NN + 1 + 255) / 256, 256, 0, stream>>>(rowptr, boff, cursor, NB_SCAN);
  scatter_part_kernel<<<8 * BPR, 256, 0, stream>>>(ei, cursor, colA, BPR);

  const int gblocks = (NN + 63) / 64;
  // layer 1
  gemm_mfma_kernel<<<gblocks, 256, 0, stream>>>(x, Bt1h, Bt1l, bufAb, NN, DIN, KP1,
                                                as1, ad1, aS, aD);
  aggregate_kernel<<<(NN + 3) / 4, 256, 0, stream>>>(rowptr, colA, aS, aD, bufAb, b1, bufB, 1);
  // layer 2
  hipMemsetAsync(aS, 0, (size_t)2 * NN * sizeof(float), stream);
  gemm_mfma_kernel<<<gblocks, 256, 0, stream>>>(bufB, Bt2h, Bt2l, bufAb, NN, DH, KP2,
                                                as2, ad2, aS, aD);
  aggregate_kernel<<<(NN + 3) / 4, 256, 0, stream>>>(rowptr, colA, aS, aD, bufAb, b2, bufB, 0);
  // pooling + head
  pool_kernel<<<(NN + 63) / 64, 128, 0, stream>>>(bufB, batch, pos, sums, cnt);
  head_kernel<<<NG, 128, 0, stream>>>(sums, cnt, Wfc, bfc, out);
}

// Round 9
// 344.352 us; speedup vs baseline: 1.9456x; 1.0590x over previous
//
#include <hip/hip_runtime.h>
#include <math.h>

#define NN 50000
#define EE 800000
#define DIN 300
#define DH 128
#define NG 128
#define RSIZE 6250  // NN/8 dst-range per XCD partition

typedef __attribute__((ext_vector_type(8))) short short8;
typedef __attribute__((ext_vector_type(4))) float floatx4;

__device__ __forceinline__ float gelu_exact(float x) {
  return 0.5f * x * (1.0f + erff(x * 0.7071067811865476f));
}

__device__ __forceinline__ void split_bf16(float v, unsigned short& hi, unsigned short& lo) {
  unsigned int u = __float_as_uint(v);
  hi = (unsigned short)(u >> 16);
  float fh = __uint_as_float((unsigned int)hi << 16);
  lo = (unsigned short)(__float_as_uint(v - fh) >> 16);
}

__device__ __forceinline__ unsigned short f2bf_rne(float x) {
  unsigned int u = __float_as_uint(x);
  unsigned int r = (u + 0x7FFFu + ((u >> 16) & 1u)) >> 16;
  return (unsigned short)r;
}

__device__ __forceinline__ float bf_lo(unsigned u) { return __uint_as_float(u << 16); }
__device__ __forceinline__ float bf_hi(unsigned u) { return __uint_as_float(u & 0xFFFF0000u); }

// async 16B global->LDS DMA (gfx950). LDS dest = wave-uniform base + lane*16.
__device__ __forceinline__ void async_ld16(void* lds, const void* g) {
  __builtin_amdgcn_global_load_lds(
      (const __attribute__((address_space(1))) unsigned int*)(unsigned long long)g,
      (__attribute__((address_space(3))) unsigned int*)(unsigned int)(unsigned long long)lds,
      16, 0, 0);
}

// ---------------- CSR build (XCD-partitioned by dst range) ----------------

__global__ __launch_bounds__(256) void count_part_kernel(const int* __restrict__ ei,
                                                         int* __restrict__ deg,
                                                         int blocksPerRange) {
  const int r = blockIdx.x & 7;
  const int t = blockIdx.x >> 3;
  const int lo = r * RSIZE, hi = lo + RSIZE;
  const int total = EE + NN;
  const int step = blocksPerRange * 256;
  for (int e0 = t * 256; e0 < total; e0 += step) {
    int e = e0 + threadIdx.x;
    if (e < total) {
      int d = (e < EE) ? ei[EE + e] : (e - EE);
      if (d >= lo && d < hi) atomicAdd(&deg[d], 1);
    }
  }
}

__global__ __launch_bounds__(1024) void scan_part_kernel(const int* __restrict__ deg,
                                                         int* __restrict__ rowptr,
                                                         int* __restrict__ bsum) {
  __shared__ int wsum[16];
  const int tid = threadIdx.x;
  const int lane = tid & 63;
  const int wid = tid >> 6;
  int idx = blockIdx.x * 1024 + tid;
  int v = (idx < NN) ? deg[idx] : 0;
  int x = v;
#pragma unroll
  for (int d = 1; d < 64; d <<= 1) {
    int y = __shfl_up(x, d, 64);
    if (lane >= d) x += y;
  }
  if (lane == 63) wsum[wid] = x;
  __syncthreads();
  if (wid == 0) {
    int s = (lane < 16) ? wsum[lane] : 0;
#pragma unroll
    for (int d = 1; d < 16; d <<= 1) {
      int y = __shfl_up(s, d, 64);
      if (lane >= d) s += y;
    }
    if (lane < 16) wsum[lane] = s;
  }
  __syncthreads();
  int woff = (wid > 0) ? wsum[wid - 1] : 0;
  int incl = x + woff;
  if (idx < NN) rowptr[idx] = incl - v;
  if (tid == 1023) bsum[blockIdx.x] = incl;
}

__global__ __launch_bounds__(64) void scan_sums_kernel(const int* __restrict__ bsum,
                                                       int* __restrict__ boff, int nb) {
  int lane = threadIdx.x;
  int v = (lane < nb) ? bsum[lane] : 0;
  int x = v;
#pragma unroll
  for (int d = 1; d < 64; d <<= 1) {
    int y = __shfl_up(x, d, 64);
    if (lane >= d) x += y;
  }
  if (lane < nb) boff[lane] = x - v;
  if (lane == nb - 1) boff[nb] = x;
}

__global__ __launch_bounds__(256) void scan_add_kernel(int* __restrict__ rowptr,
                                                       const int* __restrict__ boff,
                                                       int* __restrict__ cursor, int nb) {
  int i = blockIdx.x * 256 + threadIdx.x;
  if (i < NN) {
    int r = rowptr[i] + boff[i >> 10];
    rowptr[i] = r;
    cursor[i] = r;
  } else if (i == NN) {
    rowptr[NN] = boff[nb];
  }
}

__global__ __launch_bounds__(256) void scatter_part_kernel(const int* __restrict__ ei,
                                                           int* __restrict__ cursor,
                                                           int* __restrict__ colA,
                                                           int blocksPerRange) {
  const int r = blockIdx.x & 7;
  const int t = blockIdx.x >> 3;
  const int lo = r * RSIZE, hi = lo + RSIZE;
  const int total = EE + NN;
  const int step = blocksPerRange * 256;
  for (int e0 = t * 256; e0 < total; e0 += step) {
    int e = e0 + threadIdx.x;
    if (e < total) {
      int d = (e < EE) ? ei[EE + e] : (e - EE);
      if (d >= lo && d < hi) {
        int s = (e < EE) ? ei[e] : d;
        int p = atomicAdd(&cursor[d], 1);
        colA[p] = s;
      }
    }
  }
}

// ---------------- B pre-transpose + split to bf16 hi/lo ----------------

__global__ __launch_bounds__(256) void convert_bt_kernel(const float* __restrict__ B,
                                                         unsigned short* __restrict__ Bth,
                                                         unsigned short* __restrict__ Btl,
                                                         int K, int Kpad) {
  int i = blockIdx.x * 256 + threadIdx.x;
  int n = i / Kpad, k = i % Kpad;
  if (n >= 128) return;
  float v = (k < K) ? B[(long)k * 128 + n] : 0.f;
  unsigned short h, l;
  split_bf16(v, h, l);
  Bth[(long)n * Kpad + k] = h;
  Btl[(long)n * Kpad + k] = l;
}

// ---------------- MFMA split-bf16 GEMM + fused attention row-dots ----------------
// C (bf16) [M,128] = A[M,K] @ B[K,128]; BM=64, BN=128, BK=32.
// Wave w owns rows w*16..w*16+16 across all 8 col-tiles:
//   - A fragments load GLOBAL->REG directly (2 float4/lane), split in-register.
//   - B staged via global_load_lds DMA (pre-split bf16, no conversion needed),
//     double-buffered, XOR-swizzled (granule q^((n>>1)&3)) for 2-way LDS reads.
//   - ONE barrier per K-step; next step's DMA+A-loads issue before the MFMAs,
//     so the vmcnt drain at the barrier hides behind compute.
//   - block covers full 128-wide rows => aS/aD are plain stores (no atomics).

__global__ __launch_bounds__(256) void gemm_mfma_kernel(
    const float* __restrict__ A,
    const unsigned short* __restrict__ Bth, const unsigned short* __restrict__ Btl,
    unsigned short* __restrict__ C, int M, int K, int Kpad,
    const float* __restrict__ avs, const float* __restrict__ avd,
    float* __restrict__ aS, float* __restrict__ aD) {
  __shared__ __align__(16) unsigned short Bls[2][2][128 * 32];  // [buf][plane][n*32+k]

  const int tid = threadIdx.x;
  const int lane = tid & 63;
  const int w = tid >> 6;
  const int q = lane >> 4;
  const int m16 = lane & 15;
  const int row0 = blockIdx.x * 64;
  const int myrow = row0 + w * 16 + m16;
  const bool rok = myrow < M;
  const long abase = (long)myrow * K;

  // DMA source geometry (two 16-row instrs per plane per wave)
  const int rl = lane >> 2, qq0 = lane & 3;
  const int nb0 = w * 16 + rl;
  const int nb1 = 64 + w * 16 + rl;
  const long boff0 = (long)nb0 * Kpad + (long)((qq0 ^ ((nb0 >> 1) & 3)) * 8);
  const long boff1 = (long)nb1 * Kpad + (long)((qq0 ^ ((nb1 >> 1) & 3)) * 8);

  floatx4 acc[8];
#pragma unroll
  for (int i = 0; i < 8; i++) acc[i] = (floatx4)(0.f);

  const int nsteps = Kpad / 32;

  float4 vA0, vA1, nA0, nA1;
  nA0 = nA1 = make_float4(0.f, 0.f, 0.f, 0.f);

  auto stageB = [&](int s, int nb) {
    const int k0 = s * 32;
    async_ld16(&Bls[nb][0][(w * 16) * 32], Bth + boff0 + k0);
    async_ld16(&Bls[nb][0][(64 + w * 16) * 32], Bth + boff1 + k0);
    async_ld16(&Bls[nb][1][(w * 16) * 32], Btl + boff0 + k0);
    async_ld16(&Bls[nb][1][(64 + w * 16) * 32], Btl + boff1 + k0);
  };
  auto loadA = [&](int s, float4& x0, float4& x1) {
    const int k0 = s * 32 + q * 8;
    x0 = make_float4(0.f, 0.f, 0.f, 0.f);
    x1 = x0;
    if (rok) {
      if (k0 + 4 <= K) x0 = *(const float4*)&A[abase + k0];
      if (k0 + 8 <= K) x1 = *(const float4*)&A[abase + k0 + 4];
    }
  };

  stageB(0, 0);
  loadA(0, vA0, vA1);
  __syncthreads();  // compiler drains vmcnt before s_barrier -> DMA complete

  for (int s = 0; s < nsteps; s++) {
    const int cur = s & 1;
    if (s + 1 < nsteps) {
      stageB(s + 1, 1 ^ cur);   // async DMA, zero VGPR cost
      loadA(s + 1, nA0, nA1);   // in-flight across the MFMAs below
    }
    // split current A fragment to hi/lo bf16
    float av[8] = {vA0.x, vA0.y, vA0.z, vA0.w, vA1.x, vA1.y, vA1.z, vA1.w};
    union {
      unsigned u[4];
      short8 s8;
    } Uh, Ul;
#pragma unroll
    for (int i = 0; i < 4; i++) {
      unsigned short ha, la, hb, lb;
      split_bf16(av[2 * i], ha, la);
      split_bf16(av[2 * i + 1], hb, lb);
      Uh.u[i] = (unsigned)ha | ((unsigned)hb << 16);
      Ul.u[i] = (unsigned)la | ((unsigned)lb << 16);
    }
    short8 afh = Uh.s8, afl = Ul.s8;
#pragma unroll
    for (int ct = 0; ct < 8; ct++) {
      int n = ct * 16 + m16;
      int qv = (q ^ ((n >> 1) & 3)) * 8;
      short8 bfh = *(const short8*)&Bls[cur][0][n * 32 + qv];
      short8 bfl = *(const short8*)&Bls[cur][1][n * 32 + qv];
      acc[ct] = __builtin_amdgcn_mfma_f32_16x16x32_bf16(afh, bfh, acc[ct], 0, 0, 0);
      acc[ct] = __builtin_amdgcn_mfma_f32_16x16x32_bf16(afh, bfl, acc[ct], 0, 0, 0);
      acc[ct] = __builtin_amdgcn_mfma_f32_16x16x32_bf16(afl, bfh, acc[ct], 0, 0, 0);
    }
    vA0 = nA0;
    vA1 = nA1;
    __syncthreads();  // single barrier: drains next-step DMA (issued pre-compute)
  }

  // epilogue: C store + complete row-dots (cols fully covered by this wave)
  float avs_r[8], avd_r[8];
#pragma unroll
  for (int ct = 0; ct < 8; ct++) {
    avs_r[ct] = avs[ct * 16 + m16];
    avd_r[ct] = avd[ct * 16 + m16];
  }
#pragma unroll
  for (int reg = 0; reg < 4; reg++) {
    int grow = row0 + w * 16 + q * 4 + reg;
    bool ok = grow < M;
    float ps = 0.f, pd = 0.f;
#pragma unroll
    for (int ct = 0; ct < 8; ct++) {
      float c = acc[ct][reg];
      if (ok) C[(long)grow * 128 + ct * 16 + m16] = f2bf_rne(c);
      ps = fmaf(c, avs_r[ct], ps);
      pd = fmaf(c, avd_r[ct], pd);
    }
#pragma unroll
    for (int d = 1; d < 16; d <<= 1) {
      ps += __shfl_xor(ps, d, 64);
      pd += __shfl_xor(pd, d, 64);
    }
    if (m16 == 0 && ok) {
      aS[grow] = ps;
      aD[grow] = pd;
    }
  }
}

// ---------------- softmax attention + aggregation: one WAVE per dst ----------------

__global__ __launch_bounds__(256) void aggregate_kernel(const int* __restrict__ rowptr,
                                                        const int* __restrict__ colA,
                                                        const float* __restrict__ aS,
                                                        const float* __restrict__ aD,
                                                        const unsigned short* __restrict__ Hb,
                                                        const float* __restrict__ bias,
                                                        float* __restrict__ out,
                                                        int apply_gelu) {
  const int lane = threadIdx.x & 63;
  const int dst = blockIdx.x * 4 + (threadIdx.x >> 6);
  if (dst >= NN) return;
  const int start = rowptr[dst];
  const int end = rowptr[dst + 1];
  const int deg = end - start;
  const float ad = aD[dst];
  const int half = lane >> 5;
  const int fl = lane & 31;

  float a0 = 0.f, a1 = 0.f, a2 = 0.f, a3 = 0.f;

  if (deg <= 64) {
    int src = 0;
    float e = -__builtin_inff();
    if (lane < deg) {
      src = colA[start + lane];
      float v = aS[src] + ad;
      e = (v > 0.f) ? v : 0.2f * v;
    }
    float mx = e;
#pragma unroll
    for (int d = 1; d < 64; d <<= 1) mx = fmaxf(mx, __shfl_xor(mx, d, 64));
    float ew = (lane < deg) ? expf(e - mx) : 0.f;
    float ss = ew;
#pragma unroll
    for (int d = 1; d < 64; d <<= 1) ss += __shfl_xor(ss, d, 64);
    float wgt = ew * (1.f / ss);
    for (int j = 0; j < deg; j += 4) {
      int j0 = j + half;
      int j1 = j + 2 + half;
      int sj0 = __shfl(src, j0, 64);
      float wj0 = __shfl(wgt, j0, 64);
      int sj1 = __shfl(src, j1, 64);
      float wj1 = __shfl(wgt, j1, 64);
      uint2 u0 = *(const uint2*)&Hb[(long)sj0 * DH + fl * 4];
      uint2 u1 = *(const uint2*)&Hb[(long)sj1 * DH + fl * 4];
      a0 = fmaf(wj0, bf_lo(u0.x), a0);
      a1 = fmaf(wj0, bf_hi(u0.x), a1);
      a2 = fmaf(wj0, bf_lo(u0.y), a2);
      a3 = fmaf(wj0, bf_hi(u0.y), a3);
      a0 = fmaf(wj1, bf_lo(u1.x), a0);
      a1 = fmaf(wj1, bf_hi(u1.x), a1);
      a2 = fmaf(wj1, bf_lo(u1.y), a2);
      a3 = fmaf(wj1, bf_hi(u1.y), a3);
    }
  } else {
    float m = -__builtin_inff(), ssum = 0.f;
    for (int c0 = start; c0 < end; c0 += 64) {
      int i = c0 + lane;
      float e = -__builtin_inff();
      if (i < end) {
        int s = colA[i];
        float v = aS[s] + ad;
        e = (v > 0.f) ? v : 0.2f * v;
      }
      float cm = e;
#pragma unroll
      for (int d = 1; d < 64; d <<= 1) cm = fmaxf(cm, __shfl_xor(cm, d, 64));
      float ce = (i < end) ? expf(e - cm) : 0.f;
      float cs = ce;
#pragma unroll
      for (int d = 1; d < 64; d <<= 1) cs += __shfl_xor(cs, d, 64);
      float nm = fmaxf(m, cm);
      ssum = ssum * expf(m - nm) + cs * expf(cm - nm);
      m = nm;
    }
    float inv = 1.f / ssum;
    for (int c0 = start; c0 < end; c0 += 64) {
      int i = c0 + lane;
      int src = 0;
      float wgt = 0.f;
      if (i < end) {
        src = colA[i];
        float v = aS[src] + ad;
        float e = (v > 0.f) ? v : 0.2f * v;
        wgt = expf(e - m) * inv;
      }
      int lim = min(64, end - c0);
      for (int j = 0; j < lim; j += 4) {
        int j0 = j + half;
        int j1 = j + 2 + half;
        int sj0 = __shfl(src, j0, 64);
        float wj0 = __shfl(wgt, j0, 64);
        int sj1 = __shfl(src, j1, 64);
        float wj1 = __shfl(wgt, j1, 64);
        uint2 u0 = *(const uint2*)&Hb[(long)sj0 * DH + fl * 4];
        uint2 u1 = *(const uint2*)&Hb[(long)sj1 * DH + fl * 4];
        a0 = fmaf(wj0, bf_lo(u0.x), a0);
        a1 = fmaf(wj0, bf_hi(u0.x), a1);
        a2 = fmaf(wj0, bf_lo(u0.y), a2);
        a3 = fmaf(wj0, bf_hi(u0.y), a3);
        a0 = fmaf(wj1, bf_lo(u1.x), a0);
        a1 = fmaf(wj1, bf_hi(u1.x), a1);
        a2 = fmaf(wj1, bf_lo(u1.y), a2);
        a3 = fmaf(wj1, bf_hi(u1.y), a3);
      }
    }
  }

  a0 += __shfl_xor(a0, 32, 64);
  a1 += __shfl_xor(a1, 32, 64);
  a2 += __shfl_xor(a2, 32, 64);
  a3 += __shfl_xor(a3, 32, 64);

  if (half == 0) {
    float4 b = *(const float4*)&bias[fl * 4];
    float r0 = a0 + b.x;
    float r1 = a1 + b.y;
    float r2 = a2 + b.z;
    float r3 = a3 + b.w;
    if (apply_gelu) {
      r0 = gelu_exact(r0); r1 = gelu_exact(r1);
      r2 = gelu_exact(r2); r3 = gelu_exact(r3);
    }
    *(float4*)&out[(long)dst * DH + fl * 4] = make_float4(r0, r1, r2, r3);
  }
}

// ---------------- masked per-graph mean pooling (batch is sorted) ----------------

__global__ __launch_bounds__(128) void pool_kernel(const float* __restrict__ H,
                                                   const int* __restrict__ batch,
                                                   const int* __restrict__ pos,
                                                   float* __restrict__ sums,
                                                   float* __restrict__ cnt) {
  const int CH = 64;
  int n0 = blockIdx.x * CH;
  int n1 = min(n0 + CH, NN);
  int f = threadIdx.x;
  float acc = 0.f, c = 0.f;
  int g = batch[n0];
  for (int n = n0; n < n1; n++) {
    int gn = batch[n];
    if (gn != g) {
      atomicAdd(&sums[g * DH + f], acc);
      if (f == 0) atomicAdd(&cnt[g], c);
      acc = 0.f; c = 0.f; g = gn;
    }
    if (pos[n]) {
      acc += H[(long)n * DH + f];
      c += 1.f;
    }
  }
  atomicAdd(&sums[g * DH + f], acc);
  if (f == 0) atomicAdd(&cnt[g], c);
}

// ---------------- head ----------------

__global__ __launch_bounds__(128) void head_kernel(const float* __restrict__ sums,
                                                   const float* __restrict__ cnt,
                                                   const float* __restrict__ Wfc,
                                                   const float* __restrict__ bfc,
                                                   float* __restrict__ out) {
  int g = blockIdx.x;
  int f = threadIdx.x;
  float c = fmaxf(cnt[g], 1.f);
  float logit = sums[g * DH + f] / c;
  out[NG + g * DH + f] = logit;
  float gl = gelu_exact(logit) * Wfc[f];
  __shared__ float red[2];
#pragma unroll
  for (int d = 1; d < 64; d <<= 1) gl += __shfl_xor(gl, d, 64);
  int lane = f & 63, w = f >> 6;
  if (lane == 0) red[w] = gl;
  __syncthreads();
  if (f == 0) out[g] = red[0] + red[1] + bfc[0];
}

// ---------------- launch ----------------

extern "C" void kernel_launch(void* const* d_in, const int* in_sizes, int n_in,
                              void* d_out, int out_size, void* d_ws, size_t ws_size,
                              hipStream_t stream) {
  const float* x   = (const float*)d_in[0];
  const int* ei    = (const int*)d_in[1];
  const int* batch = (const int*)d_in[2];
  const int* pos   = (const int*)d_in[3];
  const float* W1  = (const float*)d_in[5];
  const float* as1 = (const float*)d_in[6];
  const float* ad1 = (const float*)d_in[7];
  const float* b1  = (const float*)d_in[8];
  const float* W2  = (const float*)d_in[9];
  const float* as2 = (const float*)d_in[10];
  const float* ad2 = (const float*)d_in[11];
  const float* b2  = (const float*)d_in[12];
  const float* Wfc = (const float*)d_in[13];
  const float* bfc = (const float*)d_in[14];
  float* out = (float*)d_out;

  const int KP1 = 320;
  const int KP2 = 128;
  const int NB_SCAN = (NN + 1023) / 1024;  // 49
  const int BPR = 416;                      // blocks per dst-range (x8 ranges)

  char* ws = (char*)d_ws;
  size_t off = 0;
  auto nxt = [&](size_t b) -> void* {
    size_t p = off;
    off += (b + 255) & ~(size_t)255;
    return (void*)(ws + p);
  };
  int* rowptr = (int*)nxt((NN + 1) * sizeof(int));
  int* cursor = (int*)nxt(NN * sizeof(int));
  int* colA   = (int*)nxt((size_t)(EE + NN) * sizeof(int));
  int* bsum   = (int*)nxt((NB_SCAN + 1) * sizeof(int));
  int* boff   = (int*)nxt((NB_SCAN + 1) * sizeof(int));
  float* aS   = (float*)nxt((size_t)2 * NN * sizeof(float));
  float* aD   = aS + NN;
  unsigned short* bufAb = (unsigned short*)nxt((size_t)NN * DH * sizeof(short));
  float* bufB = (float*)nxt((size_t)NN * DH * sizeof(float));
  float* sums = (float*)nxt((size_t)(NG * DH + NG) * sizeof(float));
  float* cnt  = sums + NG * DH;
  unsigned short* Bt1h = (unsigned short*)nxt((size_t)128 * KP1 * sizeof(short));
  unsigned short* Bt1l = (unsigned short*)nxt((size_t)128 * KP1 * sizeof(short));
  unsigned short* Bt2h = (unsigned short*)nxt((size_t)128 * KP2 * sizeof(short));
  unsigned short* Bt2l = (unsigned short*)nxt((size_t)128 * KP2 * sizeof(short));

  hipMemsetAsync(cursor, 0, NN * sizeof(int), stream);
  hipMemsetAsync(sums, 0, (NG * DH + NG) * sizeof(float), stream);

  convert_bt_kernel<<<(128 * KP1 + 255) / 256, 256, 0, stream>>>(W1, Bt1h, Bt1l, DIN, KP1);
  convert_bt_kernel<<<(128 * KP2 + 255) / 256, 256, 0, stream>>>(W2, Bt2h, Bt2l, DH, KP2);

  count_part_kernel<<<8 * BPR, 256, 0, stream>>>(ei, cursor, BPR);
  scan_part_kernel<<<NB_SCAN, 1024, 0, stream>>>(cursor, rowptr, bsum);
  scan_sums_kernel<<<1, 64, 0, stream>>>(bsum, boff, NB_SCAN);
  scan_add_kernel<<<(NN + 1 + 255) / 256, 256, 0, stream>>>(rowptr, boff, cursor, NB_SCAN);
  scatter_part_kernel<<<8 * BPR, 256, 0, stream>>>(ei, cursor, colA, BPR);

  const int gblocks = (NN + 63) / 64;
  // layer 1
  gemm_mfma_kernel<<<gblocks, 256, 0, stream>>>(x, Bt1h, Bt1l, bufAb, NN, DIN, KP1,
                                                as1, ad1, aS, aD);
  aggregate_kernel<<<(NN + 3) / 4, 256, 0, stream>>>(rowptr, colA, aS, aD, bufAb, b1, bufB, 1);
  // layer 2
  gemm_mfma_kernel<<<gblocks, 256, 0, stream>>>(bufB, Bt2h, Bt2l, bufAb, NN, DH, KP2,
                                                as2, ad2, aS, aD);
  aggregate_kernel<<<(NN + 3) / 4, 256, 0, stream>>>(rowptr, colA, aS, aD, bufAb, b2, bufB, 0);
  // pooling + head
  pool_kernel<<<(NN + 63) / 64, 128, 0, stream>>>(bufB, batch, pos, sums, cnt);
  head_kernel<<<NG, 128, 0, stream>>>(sums, cnt, Wfc, bfc, out);
}